// Round 1
// baseline (7429.675 us; speedup 1.0000x reference)
//
#include <hip/hip_runtime.h>
#include <math.h>

#define NN 50000
#define NE 800000
#define CH 128
#define NG 64
#define BN_EPS 1e-5f

__device__ __forceinline__ float gelu_f(float x) {
    return 0.5f * x * (1.0f + erff(x * 0.70710678118654752440f));
}

// ---------------- degree / norm ----------------
__global__ __launch_bounds__(256) void edge_deg_k(const int* __restrict__ ei, float* __restrict__ deg) {
    int e = blockIdx.x * 256 + threadIdx.x;
    if (e < NE) atomicAdd(&deg[ei[NE + e]], 1.0f);
}

__global__ __launch_bounds__(256) void dinv_k(const float* __restrict__ deg, float* __restrict__ dinv) {
    int i = blockIdx.x * 256 + threadIdx.x;
    if (i < NN) dinv[i] = rsqrtf(deg[i] + 1.0f);  // +1 = self loop; always > 0
}

// ---------------- GEMM: out[N,128] = A[N,128] @ W[128,128] ----------------
__global__ __launch_bounds__(256) void gemm_k(const float* __restrict__ A,
                                              const float* __restrict__ W,
                                              float* __restrict__ out) {
    __shared__ float At[32 * 128];
    const int tid = threadIdx.x;
    const int row0 = blockIdx.x * 32;

    // load 32x128 A tile as float4 (zero-pad OOB rows)
    #pragma unroll
    for (int i = 0; i < 4; ++i) {
        int idx = tid + i * 256;         // float4 index in [0,1024)
        int r = idx >> 5;                // 32 float4 per row
        float4 v = make_float4(0.f, 0.f, 0.f, 0.f);
        if (row0 + r < NN) v = ((const float4*)A)[(size_t)(row0 + r) * 32 + (idx & 31)];
        ((float4*)At)[idx] = v;
    }
    __syncthreads();

    const int c0 = (tid & 63) * 2;   // 2 consecutive cols
    const int rg = tid >> 6;         // 4 groups x 8 rows

    float acc0[8], acc1[8];
    #pragma unroll
    for (int i = 0; i < 8; ++i) { acc0[i] = 0.f; acc1[i] = 0.f; }

    for (int k4 = 0; k4 < 32; ++k4) {
        float2 w0 = *(const float2*)&W[(k4 * 4 + 0) * 128 + c0];
        float2 w1 = *(const float2*)&W[(k4 * 4 + 1) * 128 + c0];
        float2 w2 = *(const float2*)&W[(k4 * 4 + 2) * 128 + c0];
        float2 w3 = *(const float2*)&W[(k4 * 4 + 3) * 128 + c0];
        #pragma unroll
        for (int i = 0; i < 8; ++i) {
            float4 a = *(const float4*)&At[(rg * 8 + i) * 128 + k4 * 4];
            acc0[i] += a.x * w0.x + a.y * w1.x + a.z * w2.x + a.w * w3.x;
            acc1[i] += a.x * w0.y + a.y * w1.y + a.z * w2.y + a.w * w3.y;
        }
    }
    #pragma unroll
    for (int i = 0; i < 8; ++i) {
        int r = row0 + rg * 8 + i;
        if (r < NN) *(float2*)&out[(size_t)r * 128 + c0] = make_float2(acc0[i], acc1[i]);
    }
}

// ---------------- init agg = bias + self-loop term ----------------
__global__ __launch_bounds__(256) void init_agg_k(const float* __restrict__ hw,
                                                  const float* __restrict__ bias,
                                                  const float* __restrict__ dinv,
                                                  float* __restrict__ agg) {
    int idx = blockIdx.x * 256 + threadIdx.x;   // float4 index, NN*32 total
    if (idx >= NN * 32) return;
    int node = idx >> 5;
    int q = idx & 31;
    float d = dinv[node];
    float d2 = d * d;
    float4 h = ((const float4*)hw)[idx];
    float4 b = ((const float4*)bias)[q];
    ((float4*)agg)[idx] = make_float4(b.x + h.x * d2, b.y + h.y * d2,
                                      b.z + h.z * d2, b.w + h.w * d2);
}

// ---------------- edge aggregation (atomics) ----------------
__global__ __launch_bounds__(256) void edge_agg_k(const int* __restrict__ ei,
                                                  const float* __restrict__ dinv,
                                                  const float* __restrict__ hw,
                                                  float* __restrict__ agg) {
    int t = blockIdx.x * 256 + threadIdx.x;
    int e = t >> 5;                  // 32 threads per edge
    if (e >= NE) return;
    int q = t & 31;                  // float4 slot
    int src = ei[e];
    int dst = ei[NE + e];
    float w = dinv[src] * dinv[dst];
    float4 v = ((const float4*)hw)[(size_t)src * 32 + q];
    float* p = &agg[(size_t)dst * 128 + q * 4];
    atomicAdd(p + 0, v.x * w);
    atomicAdd(p + 1, v.y * w);
    atomicAdd(p + 2, v.z * w);
    atomicAdd(p + 3, v.w * w);
}

// ---------------- batchnorm ----------------
__global__ __launch_bounds__(256) void bn_stats_k(const float* __restrict__ h, float* __restrict__ sums) {
    int c = threadIdx.x & 127;
    int half = threadIdx.x >> 7;
    int r0 = blockIdx.x * 128 + half;
    float s = 0.f, ss = 0.f;
    #pragma unroll 4
    for (int i = 0; i < 64; ++i) {
        int r = r0 + i * 2;
        if (r < NN) {
            float v = h[(size_t)r * 128 + c];
            s += v; ss += v * v;
        }
    }
    __shared__ float sh_s[128], sh_ss[128];
    if (half == 1) { sh_s[c] = s; sh_ss[c] = ss; }
    __syncthreads();
    if (half == 0) {
        atomicAdd(&sums[c], s + sh_s[c]);
        atomicAdd(&sums[128 + c], ss + sh_ss[c]);
    }
}

__global__ __launch_bounds__(128) void bn_finalize_k(const float* __restrict__ sums,
                                                     const float* __restrict__ g,
                                                     const float* __restrict__ beta,
                                                     float* __restrict__ ss) {
    int c = threadIdx.x;
    float mean = sums[c] * (1.0f / NN);
    float var = sums[128 + c] * (1.0f / NN) - mean * mean;
    float sc = g[c] * rsqrtf(var + BN_EPS);
    ss[c] = sc;
    ss[128 + c] = beta[c] - mean * sc;
}

__global__ __launch_bounds__(256) void bn_apply_gelu_k(float* __restrict__ h, const float* __restrict__ ss) {
    int idx = blockIdx.x * 256 + threadIdx.x;   // float4 index
    if (idx >= NN * 32) return;
    int q = idx & 31;
    float4 v = ((float4*)h)[idx];
    float4 sc = ((const float4*)ss)[q];
    float4 sh = ((const float4*)ss)[32 + q];
    v.x = gelu_f(v.x * sc.x + sh.x);
    v.y = gelu_f(v.y * sc.y + sh.y);
    v.z = gelu_f(v.z * sc.z + sh.z);
    v.w = gelu_f(v.w * sc.w + sh.w);
    ((float4*)h)[idx] = v;
}

// ---------------- global mean pool (sorted batch, binary search) ----------------
__device__ __forceinline__ int lower_bound_dev(const int* __restrict__ a, int n, int key) {
    int lo = 0, hi = n;
    while (lo < hi) {
        int mid = (lo + hi) >> 1;
        if (a[mid] < key) lo = mid + 1; else hi = mid;
    }
    return lo;
}

__global__ __launch_bounds__(128) void pool_k(const float* __restrict__ h,
                                              const int* __restrict__ batch,
                                              float* __restrict__ pooled) {
    int g = blockIdx.x;
    int a = lower_bound_dev(batch, NN, g);
    int b = lower_bound_dev(batch, NN, g + 1);
    int c = threadIdx.x;
    float s = 0.f;
    for (int r = a; r < b; ++r) s += h[(size_t)r * 128 + c];
    float cnt = (float)(b - a);
    pooled[g * 128 + c] = s / fmaxf(cnt, 1.0f);
}

// ---------------- MLP head (fused, tiny) ----------------
__global__ __launch_bounds__(128) void head_k(const float* __restrict__ pooled,
                                              const float* __restrict__ W0, const float* __restrict__ b0,
                                              const float* __restrict__ W1, const float* __restrict__ b1,
                                              const float* __restrict__ W2, const float* __restrict__ b2,
                                              float* __restrict__ out) {
    __shared__ float r0[128], r1[128];
    int g = blockIdx.x, t = threadIdx.x;
    r0[t] = pooled[g * 128 + t];
    __syncthreads();
    float acc = b0[t];
    for (int k = 0; k < 128; ++k) acc += r0[k] * W0[k * 128 + t];
    r1[t] = gelu_f(acc);
    __syncthreads();
    acc = b1[t];
    for (int k = 0; k < 128; ++k) acc += r1[k] * W1[k * 128 + t];
    float y = gelu_f(acc);
    __syncthreads();
    r0[t] = y;
    __syncthreads();
    if (t < 10) {
        acc = b2[t];
        for (int k = 0; k < 128; ++k) acc += r0[k] * W2[k * 10 + t];
        out[g * 10 + t] = acc;
    }
}

extern "C" void kernel_launch(void* const* d_in, const int* in_sizes, int n_in,
                              void* d_out, int out_size, void* d_ws, size_t ws_size,
                              hipStream_t stream) {
    const float* x      = (const float*)d_in[0];
    const int*   ei     = (const int*)d_in[1];
    const int*   batch  = (const int*)d_in[2];
    const float* Wb0    = (const float*)d_in[4];
    const float* bb0    = (const float*)d_in[5];
    const float* gb0    = (const float*)d_in[6];
    const float* betab0 = (const float*)d_in[7];
    const float* Wb1    = (const float*)d_in[8];
    const float* bb1    = (const float*)d_in[9];
    const float* Wa0    = (const float*)d_in[10];
    const float* ba0    = (const float*)d_in[11];
    const float* ga0    = (const float*)d_in[12];
    const float* bea0   = (const float*)d_in[13];
    const float* Wa1    = (const float*)d_in[14];
    const float* ba1    = (const float*)d_in[15];
    const float* ga1    = (const float*)d_in[16];
    const float* bea1   = (const float*)d_in[17];
    const float* Wa2    = (const float*)d_in[18];
    const float* ba2    = (const float*)d_in[19];
    const float* Wh0    = (const float*)d_in[20];
    const float* bh0    = (const float*)d_in[21];
    const float* Wh1    = (const float*)d_in[22];
    const float* bh1    = (const float*)d_in[23];
    const float* Wh2    = (const float*)d_in[24];
    const float* bh2    = (const float*)d_in[25];
    float* out = (float*)d_out;

    float* ws = (float*)d_ws;
    float* bufA   = ws;                      // hw scratch, 6.4M floats
    float* bufB   = bufA + (size_t)NN * CH;
    float* bufC   = bufB + (size_t)NN * CH;
    float* deg    = bufC + (size_t)NN * CH;  // 50000
    float* dinv   = deg + NN;                // 50000
    float* bnss   = dinv + NN;               // 256: sums / sumsq
    float* ssbuf  = bnss + 256;              // 256: scale / shift
    float* pooled = ssbuf + 256;             // 8192

    // degrees + normalization
    hipMemsetAsync(deg, 0, NN * sizeof(float), stream);
    edge_deg_k<<<(NE + 255) / 256, 256, 0, stream>>>(ei, deg);
    dinv_k<<<(NN + 255) / 256, 256, 0, stream>>>(deg, dinv);

    auto conv = [&](const float* in, const float* W, const float* b, float* o) {
        gemm_k<<<(NN + 31) / 32, 256, 0, stream>>>(in, W, bufA);
        init_agg_k<<<(NN * 32) / 256, 256, 0, stream>>>(bufA, b, dinv, o);
        edge_agg_k<<<(NE * 32) / 256, 256, 0, stream>>>(ei, dinv, bufA, o);
    };
    auto bn_gelu = [&](float* h, const float* g, const float* beta) {
        hipMemsetAsync(bnss, 0, 256 * sizeof(float), stream);
        bn_stats_k<<<(NN + 127) / 128, 256, 0, stream>>>(h, bnss);
        bn_finalize_k<<<1, 128, 0, stream>>>(bnss, g, beta, ssbuf);
        bn_apply_gelu_k<<<(NN * 32) / 256, 256, 0, stream>>>(h, ssbuf);
    };

    conv(x, Wb0, bb0, bufB);
    bn_gelu(bufB, gb0, betab0);
    conv(bufB, Wb1, bb1, bufC);
    conv(bufC, Wa0, ba0, bufB);
    bn_gelu(bufB, ga0, bea0);
    conv(bufB, Wa1, ba1, bufC);
    bn_gelu(bufC, ga1, bea1);
    conv(bufC, Wa2, ba2, bufB);

    pool_k<<<NG, 128, 0, stream>>>(bufB, batch, pooled);
    head_k<<<NG, 128, 0, stream>>>(pooled, Wh0, bh0, Wh1, bh1, Wh2, bh2, out);
}

// Round 2
// 1184.818 us; speedup vs baseline: 6.2707x; 6.2707x over previous
//
#include <hip/hip_runtime.h>
#include <math.h>

#define NN 50000
#define NE 800000
#define CH 128
#define NG 64
#define BN_EPS 1e-5f

__device__ __forceinline__ float gelu_f(float x) {
    return 0.5f * x * (1.0f + erff(x * 0.70710678118654752440f));
}

// ---------------- degree histogram (int) ----------------
__global__ __launch_bounds__(256) void hist_k(const int* __restrict__ ei, int* __restrict__ cnt) {
    int e = blockIdx.x * 256 + threadIdx.x;
    if (e < NE) atomicAdd(&cnt[ei[NE + e]], 1);
}

__global__ __launch_bounds__(256) void dinv_k(const int* __restrict__ cnt, float* __restrict__ dinv) {
    int i = blockIdx.x * 256 + threadIdx.x;
    if (i < NN) dinv[i] = rsqrtf((float)cnt[i] + 1.0f);  // +1 = self loop
}

// ---------------- exclusive scan over 50000 counts (1 block) ----------------
__global__ __launch_bounds__(1024) void scan_k(const int* __restrict__ cnt,
                                               int* __restrict__ row_ptr,
                                               int* __restrict__ fill) {
    const int T = 1024;
    const int PER = (NN + T - 1) / T;  // 49
    int t = threadIdx.x;
    int base = t * PER;
    int s = 0;
    for (int i = 0; i < PER; ++i) {
        int idx = base + i;
        if (idx < NN) s += cnt[idx];
    }
    __shared__ int sh[1024];
    sh[t] = s;
    __syncthreads();
    for (int off = 1; off < 1024; off <<= 1) {
        int v = (t >= off) ? sh[t - off] : 0;
        __syncthreads();
        sh[t] += v;
        __syncthreads();
    }
    int pre = (t == 0) ? 0 : sh[t - 1];
    for (int i = 0; i < PER; ++i) {
        int idx = base + i;
        if (idx < NN) {
            row_ptr[idx] = pre;
            pre += cnt[idx];
            fill[idx] = 0;
        }
    }
    if (t == 1023) row_ptr[NN] = sh[1023];
}

// ---------------- scatter edges into CSR slots ----------------
__global__ __launch_bounds__(256) void scatter_k(const int* __restrict__ ei,
                                                 const float* __restrict__ dinv,
                                                 const int* __restrict__ row_ptr,
                                                 int* __restrict__ fill,
                                                 int* __restrict__ csr_src,
                                                 float* __restrict__ csr_w) {
    int e = blockIdx.x * 256 + threadIdx.x;
    if (e >= NE) return;
    int s = ei[e];
    int d = ei[NE + e];
    int pos = row_ptr[d] + atomicAdd(&fill[d], 1);
    csr_src[pos] = s;
    csr_w[pos] = dinv[s] * dinv[d];
}

// ---------------- GEMM: out[N,128] = A[N,128] @ W[128,128] ----------------
__global__ __launch_bounds__(256) void gemm_k(const float* __restrict__ A,
                                              const float* __restrict__ W,
                                              float* __restrict__ out) {
    __shared__ float At[32 * 128];
    const int tid = threadIdx.x;
    const int row0 = blockIdx.x * 32;

    #pragma unroll
    for (int i = 0; i < 4; ++i) {
        int idx = tid + i * 256;
        int r = idx >> 5;
        float4 v = make_float4(0.f, 0.f, 0.f, 0.f);
        if (row0 + r < NN) v = ((const float4*)A)[(size_t)(row0 + r) * 32 + (idx & 31)];
        ((float4*)At)[idx] = v;
    }
    __syncthreads();

    const int c0 = (tid & 63) * 2;
    const int rg = tid >> 6;

    float acc0[8], acc1[8];
    #pragma unroll
    for (int i = 0; i < 8; ++i) { acc0[i] = 0.f; acc1[i] = 0.f; }

    for (int k4 = 0; k4 < 32; ++k4) {
        float2 w0 = *(const float2*)&W[(k4 * 4 + 0) * 128 + c0];
        float2 w1 = *(const float2*)&W[(k4 * 4 + 1) * 128 + c0];
        float2 w2 = *(const float2*)&W[(k4 * 4 + 2) * 128 + c0];
        float2 w3 = *(const float2*)&W[(k4 * 4 + 3) * 128 + c0];
        #pragma unroll
        for (int i = 0; i < 8; ++i) {
            float4 a = *(const float4*)&At[(rg * 8 + i) * 128 + k4 * 4];
            acc0[i] += a.x * w0.x + a.y * w1.x + a.z * w2.x + a.w * w3.x;
            acc1[i] += a.x * w0.y + a.y * w1.y + a.z * w2.y + a.w * w3.y;
        }
    }
    #pragma unroll
    for (int i = 0; i < 8; ++i) {
        int r = row0 + rg * 8 + i;
        if (r < NN) *(float2*)&out[(size_t)r * 128 + c0] = make_float2(acc0[i], acc1[i]);
    }
}

// ---------------- CSR aggregation: one wave per node, fused bias+self-loop ----------------
__global__ __launch_bounds__(256) void csr_agg_k(const int* __restrict__ row_ptr,
                                                 const int* __restrict__ csr_src,
                                                 const float* __restrict__ csr_w,
                                                 const float* __restrict__ hw,
                                                 const float* __restrict__ bias,
                                                 const float* __restrict__ dinv,
                                                 float* __restrict__ out) {
    int node = (blockIdx.x * 256 + threadIdx.x) >> 6;
    if (node >= NN) return;
    int lane = threadIdx.x & 63;

    const float2* hw2 = (const float2*)hw;
    float di = dinv[node];
    float sw = di * di;
    float2 b = ((const float2*)bias)[lane];
    float2 h = hw2[(size_t)node * 64 + lane];
    float2 acc = make_float2(b.x + h.x * sw, b.y + h.y * sw);

    int j = row_ptr[node];
    int j1 = row_ptr[node + 1];
    for (; j + 1 < j1; j += 2) {
        int s0 = csr_src[j], s1 = csr_src[j + 1];
        float w0 = csr_w[j], w1 = csr_w[j + 1];
        float2 v0 = hw2[(size_t)s0 * 64 + lane];
        float2 v1 = hw2[(size_t)s1 * 64 + lane];
        acc.x += v0.x * w0 + v1.x * w1;
        acc.y += v0.y * w0 + v1.y * w1;
    }
    if (j < j1) {
        int s = csr_src[j];
        float w = csr_w[j];
        float2 v = hw2[(size_t)s * 64 + lane];
        acc.x += v.x * w;
        acc.y += v.y * w;
    }
    ((float2*)out)[(size_t)node * 64 + lane] = acc;
}

// ---------------- batchnorm ----------------
__global__ __launch_bounds__(256) void bn_stats_k(const float* __restrict__ h, float* __restrict__ sums) {
    int c = threadIdx.x & 127;
    int half = threadIdx.x >> 7;
    int r0 = blockIdx.x * 128 + half;
    float s = 0.f, ss = 0.f;
    #pragma unroll 4
    for (int i = 0; i < 64; ++i) {
        int r = r0 + i * 2;
        if (r < NN) {
            float v = h[(size_t)r * 128 + c];
            s += v; ss += v * v;
        }
    }
    __shared__ float sh_s[128], sh_ss[128];
    if (half == 1) { sh_s[c] = s; sh_ss[c] = ss; }
    __syncthreads();
    if (half == 0) {
        atomicAdd(&sums[c], s + sh_s[c]);
        atomicAdd(&sums[128 + c], ss + sh_ss[c]);
    }
}

__global__ __launch_bounds__(128) void bn_finalize_k(const float* __restrict__ sums,
                                                     const float* __restrict__ g,
                                                     const float* __restrict__ beta,
                                                     float* __restrict__ ss) {
    int c = threadIdx.x;
    float mean = sums[c] * (1.0f / NN);
    float var = sums[128 + c] * (1.0f / NN) - mean * mean;
    float sc = g[c] * rsqrtf(var + BN_EPS);
    ss[c] = sc;
    ss[128 + c] = beta[c] - mean * sc;
}

__global__ __launch_bounds__(256) void bn_apply_gelu_k(float* __restrict__ h, const float* __restrict__ ss) {
    int idx = blockIdx.x * 256 + threadIdx.x;
    if (idx >= NN * 32) return;
    int q = idx & 31;
    float4 v = ((float4*)h)[idx];
    float4 sc = ((const float4*)ss)[q];
    float4 sh = ((const float4*)ss)[32 + q];
    v.x = gelu_f(v.x * sc.x + sh.x);
    v.y = gelu_f(v.y * sc.y + sh.y);
    v.z = gelu_f(v.z * sc.z + sh.z);
    v.w = gelu_f(v.w * sc.w + sh.w);
    ((float4*)h)[idx] = v;
}

// ---------------- global mean pool ----------------
__device__ __forceinline__ int lower_bound_dev(const int* __restrict__ a, int n, int key) {
    int lo = 0, hi = n;
    while (lo < hi) {
        int mid = (lo + hi) >> 1;
        if (a[mid] < key) lo = mid + 1; else hi = mid;
    }
    return lo;
}

__global__ __launch_bounds__(128) void pool_k(const float* __restrict__ h,
                                              const int* __restrict__ batch,
                                              float* __restrict__ pooled) {
    int g = blockIdx.x;
    int a = lower_bound_dev(batch, NN, g);
    int b = lower_bound_dev(batch, NN, g + 1);
    int c = threadIdx.x;
    float s = 0.f;
    for (int r = a; r < b; ++r) s += h[(size_t)r * 128 + c];
    float cnt = (float)(b - a);
    pooled[g * 128 + c] = s / fmaxf(cnt, 1.0f);
}

// ---------------- MLP head ----------------
__global__ __launch_bounds__(128) void head_k(const float* __restrict__ pooled,
                                              const float* __restrict__ W0, const float* __restrict__ b0,
                                              const float* __restrict__ W1, const float* __restrict__ b1,
                                              const float* __restrict__ W2, const float* __restrict__ b2,
                                              float* __restrict__ out) {
    __shared__ float r0[128], r1[128];
    int g = blockIdx.x, t = threadIdx.x;
    r0[t] = pooled[g * 128 + t];
    __syncthreads();
    float acc = b0[t];
    for (int k = 0; k < 128; ++k) acc += r0[k] * W0[k * 128 + t];
    r1[t] = gelu_f(acc);
    __syncthreads();
    acc = b1[t];
    for (int k = 0; k < 128; ++k) acc += r1[k] * W1[k * 128 + t];
    float y = gelu_f(acc);
    __syncthreads();
    r0[t] = y;
    __syncthreads();
    if (t < 10) {
        acc = b2[t];
        for (int k = 0; k < 128; ++k) acc += r0[k] * W2[k * 10 + t];
        out[g * 10 + t] = acc;
    }
}

extern "C" void kernel_launch(void* const* d_in, const int* in_sizes, int n_in,
                              void* d_out, int out_size, void* d_ws, size_t ws_size,
                              hipStream_t stream) {
    const float* x      = (const float*)d_in[0];
    const int*   ei     = (const int*)d_in[1];
    const int*   batch  = (const int*)d_in[2];
    const float* Wb0    = (const float*)d_in[4];
    const float* bb0    = (const float*)d_in[5];
    const float* gb0    = (const float*)d_in[6];
    const float* betab0 = (const float*)d_in[7];
    const float* Wb1    = (const float*)d_in[8];
    const float* bb1    = (const float*)d_in[9];
    const float* Wa0    = (const float*)d_in[10];
    const float* ba0    = (const float*)d_in[11];
    const float* ga0    = (const float*)d_in[12];
    const float* bea0   = (const float*)d_in[13];
    const float* Wa1    = (const float*)d_in[14];
    const float* ba1    = (const float*)d_in[15];
    const float* ga1    = (const float*)d_in[16];
    const float* bea1   = (const float*)d_in[17];
    const float* Wa2    = (const float*)d_in[18];
    const float* ba2    = (const float*)d_in[19];
    const float* Wh0    = (const float*)d_in[20];
    const float* bh0    = (const float*)d_in[21];
    const float* Wh1    = (const float*)d_in[22];
    const float* bh1    = (const float*)d_in[23];
    const float* Wh2    = (const float*)d_in[24];
    const float* bh2    = (const float*)d_in[25];
    float* out = (float*)d_out;

    char* ws = (char*)d_ws;
    float* bufA    = (float*)ws;                       ws += (size_t)NN * CH * 4;
    float* bufB    = (float*)ws;                       ws += (size_t)NN * CH * 4;
    float* bufC    = (float*)ws;                       ws += (size_t)NN * CH * 4;
    int*   cnt     = (int*)ws;                         ws += (size_t)NN * 4;
    float* dinv    = (float*)ws;                       ws += (size_t)NN * 4;
    int*   row_ptr = (int*)ws;                         ws += (size_t)(NN + 1) * 4;
    int*   fill    = (int*)ws;                         ws += (size_t)NN * 4;
    int*   csr_src = (int*)ws;                         ws += (size_t)NE * 4;
    float* csr_w   = (float*)ws;                       ws += (size_t)NE * 4;
    float* bnss    = (float*)ws;                       ws += 256 * 4;
    float* ssbuf   = (float*)ws;                       ws += 256 * 4;
    float* pooled  = (float*)ws;                       ws += (size_t)NG * CH * 4;

    // CSR build
    hipMemsetAsync(cnt, 0, NN * sizeof(int), stream);
    hist_k<<<(NE + 255) / 256, 256, 0, stream>>>(ei, cnt);
    dinv_k<<<(NN + 255) / 256, 256, 0, stream>>>(cnt, dinv);
    scan_k<<<1, 1024, 0, stream>>>(cnt, row_ptr, fill);
    scatter_k<<<(NE + 255) / 256, 256, 0, stream>>>(ei, dinv, row_ptr, fill, csr_src, csr_w);

    auto conv = [&](const float* in, const float* W, const float* b, float* o) {
        gemm_k<<<(NN + 31) / 32, 256, 0, stream>>>(in, W, bufA);
        csr_agg_k<<<(NN * 64 + 255) / 256, 256, 0, stream>>>(row_ptr, csr_src, csr_w, bufA, b, dinv, o);
    };
    auto bn_gelu = [&](float* h, const float* g, const float* beta) {
        hipMemsetAsync(bnss, 0, 256 * sizeof(float), stream);
        bn_stats_k<<<(NN + 127) / 128, 256, 0, stream>>>(h, bnss);
        bn_finalize_k<<<1, 128, 0, stream>>>(bnss, g, beta, ssbuf);
        bn_apply_gelu_k<<<(NN * 32) / 256, 256, 0, stream>>>(h, ssbuf);
    };

    conv(x, Wb0, bb0, bufB);
    bn_gelu(bufB, gb0, betab0);
    conv(bufB, Wb1, bb1, bufC);
    conv(bufC, Wa0, ba0, bufB);
    bn_gelu(bufB, ga0, bea0);
    conv(bufB, Wa1, ba1, bufC);
    bn_gelu(bufC, ga1, bea1);
    conv(bufC, Wa2, ba2, bufB);

    pool_k<<<NG, 128, 0, stream>>>(bufB, batch, pooled);
    head_k<<<NG, 128, 0, stream>>>(pooled, Wh0, bh0, Wh1, bh1, Wh2, bh2, out);
}

// Round 3
// 999.832 us; speedup vs baseline: 7.4309x; 1.1850x over previous
//
#include <hip/hip_runtime.h>
#include <math.h>

#define NN 50000
#define NE 800000
#define CH 128
#define NG 64
#define BN_EPS 1e-5f
#define POOL_CHUNK 64

__device__ __forceinline__ float gelu_f(float x) {
    return 0.5f * x * (1.0f + erff(x * 0.70710678118654752440f));
}

// ---------------- degree histogram (int) ----------------
__global__ __launch_bounds__(256) void hist_k(const int* __restrict__ ei, int* __restrict__ cnt) {
    int e = blockIdx.x * 256 + threadIdx.x;
    if (e < NE) atomicAdd(&cnt[ei[NE + e]], 1);
}

__global__ __launch_bounds__(256) void dinv_k(const int* __restrict__ cnt, float* __restrict__ dinv) {
    int i = blockIdx.x * 256 + threadIdx.x;
    if (i < NN) dinv[i] = rsqrtf((float)cnt[i] + 1.0f);  // +1 = self loop
}

// ---------------- exclusive scan over 50000 counts (1 block) ----------------
__global__ __launch_bounds__(1024) void scan_k(const int* __restrict__ cnt,
                                               int* __restrict__ row_ptr,
                                               int* __restrict__ fill) {
    const int T = 1024;
    const int PER = (NN + T - 1) / T;  // 49
    int t = threadIdx.x;
    int base = t * PER;
    int s = 0;
    for (int i = 0; i < PER; ++i) {
        int idx = base + i;
        if (idx < NN) s += cnt[idx];
    }
    __shared__ int sh[1024];
    sh[t] = s;
    __syncthreads();
    for (int off = 1; off < 1024; off <<= 1) {
        int v = (t >= off) ? sh[t - off] : 0;
        __syncthreads();
        sh[t] += v;
        __syncthreads();
    }
    int pre = (t == 0) ? 0 : sh[t - 1];
    for (int i = 0; i < PER; ++i) {
        int idx = base + i;
        if (idx < NN) {
            row_ptr[idx] = pre;
            pre += cnt[idx];
            fill[idx] = 0;
        }
    }
    if (t == 1023) row_ptr[NN] = sh[1023];
}

// ---------------- scatter edges into CSR slots ----------------
__global__ __launch_bounds__(256) void scatter_k(const int* __restrict__ ei,
                                                 const float* __restrict__ dinv,
                                                 const int* __restrict__ row_ptr,
                                                 int* __restrict__ fill,
                                                 int* __restrict__ csr_src,
                                                 float* __restrict__ csr_w) {
    int e = blockIdx.x * 256 + threadIdx.x;
    if (e >= NE) return;
    int s = ei[e];
    int d = ei[NE + e];
    int pos = row_ptr[d] + atomicAdd(&fill[d], 1);
    csr_src[pos] = s;
    csr_w[pos] = dinv[s] * dinv[d];
}

// ---------------- GEMM: out[N,128] = A[N,128] @ W[128,128] ----------------
__global__ __launch_bounds__(256) void gemm_k(const float* __restrict__ A,
                                              const float* __restrict__ W,
                                              float* __restrict__ out) {
    __shared__ float At[32 * 128];
    const int tid = threadIdx.x;
    const int row0 = blockIdx.x * 32;

    #pragma unroll
    for (int i = 0; i < 4; ++i) {
        int idx = tid + i * 256;
        int r = idx >> 5;
        float4 v = make_float4(0.f, 0.f, 0.f, 0.f);
        if (row0 + r < NN) v = ((const float4*)A)[(size_t)(row0 + r) * 32 + (idx & 31)];
        ((float4*)At)[idx] = v;
    }
    __syncthreads();

    const int c0 = (tid & 63) * 2;
    const int rg = tid >> 6;

    float acc0[8], acc1[8];
    #pragma unroll
    for (int i = 0; i < 8; ++i) { acc0[i] = 0.f; acc1[i] = 0.f; }

    for (int k4 = 0; k4 < 32; ++k4) {
        float2 w0 = *(const float2*)&W[(k4 * 4 + 0) * 128 + c0];
        float2 w1 = *(const float2*)&W[(k4 * 4 + 1) * 128 + c0];
        float2 w2 = *(const float2*)&W[(k4 * 4 + 2) * 128 + c0];
        float2 w3 = *(const float2*)&W[(k4 * 4 + 3) * 128 + c0];
        #pragma unroll
        for (int i = 0; i < 8; ++i) {
            float4 a = *(const float4*)&At[(rg * 8 + i) * 128 + k4 * 4];
            acc0[i] += a.x * w0.x + a.y * w1.x + a.z * w2.x + a.w * w3.x;
            acc1[i] += a.x * w0.y + a.y * w1.y + a.z * w2.y + a.w * w3.y;
        }
    }
    #pragma unroll
    for (int i = 0; i < 8; ++i) {
        int r = row0 + rg * 8 + i;
        if (r < NN) *(float2*)&out[(size_t)r * 128 + c0] = make_float2(acc0[i], acc1[i]);
    }
}

// ---------------- CSR aggregation: one wave per node, fused bias+self-loop ----------------
__global__ __launch_bounds__(256) void csr_agg_k(const int* __restrict__ row_ptr,
                                                 const int* __restrict__ csr_src,
                                                 const float* __restrict__ csr_w,
                                                 const float* __restrict__ hw,
                                                 const float* __restrict__ bias,
                                                 const float* __restrict__ dinv,
                                                 float* __restrict__ out) {
    int node = (blockIdx.x * 256 + threadIdx.x) >> 6;
    if (node >= NN) return;
    int lane = threadIdx.x & 63;

    const float2* hw2 = (const float2*)hw;
    float di = dinv[node];
    float sw = di * di;
    float2 b = ((const float2*)bias)[lane];
    float2 h = hw2[(size_t)node * 64 + lane];
    float2 acc = make_float2(b.x + h.x * sw, b.y + h.y * sw);

    int j = row_ptr[node];
    int j1 = row_ptr[node + 1];
    for (; j + 1 < j1; j += 2) {
        int s0 = csr_src[j], s1 = csr_src[j + 1];
        float w0 = csr_w[j], w1 = csr_w[j + 1];
        float2 v0 = hw2[(size_t)s0 * 64 + lane];
        float2 v1 = hw2[(size_t)s1 * 64 + lane];
        acc.x += v0.x * w0 + v1.x * w1;
        acc.y += v0.y * w0 + v1.y * w1;
    }
    if (j < j1) {
        int s = csr_src[j];
        float w = csr_w[j];
        float2 v = hw2[(size_t)s * 64 + lane];
        acc.x += v.x * w;
        acc.y += v.y * w;
    }
    ((float2*)out)[(size_t)node * 64 + lane] = acc;
}

// ---------------- batchnorm ----------------
__global__ __launch_bounds__(256) void bn_stats_k(const float* __restrict__ h, float* __restrict__ sums) {
    int c = threadIdx.x & 127;
    int half = threadIdx.x >> 7;
    int r0 = blockIdx.x * 128 + half;
    float s = 0.f, ss = 0.f;
    #pragma unroll 4
    for (int i = 0; i < 64; ++i) {
        int r = r0 + i * 2;
        if (r < NN) {
            float v = h[(size_t)r * 128 + c];
            s += v; ss += v * v;
        }
    }
    __shared__ float sh_s[128], sh_ss[128];
    if (half == 1) { sh_s[c] = s; sh_ss[c] = ss; }
    __syncthreads();
    if (half == 0) {
        atomicAdd(&sums[c], s + sh_s[c]);
        atomicAdd(&sums[128 + c], ss + sh_ss[c]);
    }
}

__global__ __launch_bounds__(128) void bn_finalize_k(const float* __restrict__ sums,
                                                     const float* __restrict__ g,
                                                     const float* __restrict__ beta,
                                                     float* __restrict__ ss) {
    int c = threadIdx.x;
    float mean = sums[c] * (1.0f / NN);
    float var = sums[128 + c] * (1.0f / NN) - mean * mean;
    float sc = g[c] * rsqrtf(var + BN_EPS);
    ss[c] = sc;
    ss[128 + c] = beta[c] - mean * sc;
}

__global__ __launch_bounds__(256) void bn_apply_gelu_k(float* __restrict__ h, const float* __restrict__ ss) {
    int idx = blockIdx.x * 256 + threadIdx.x;
    if (idx >= NN * 32) return;
    int q = idx & 31;
    float4 v = ((float4*)h)[idx];
    float4 sc = ((const float4*)ss)[q];
    float4 sh = ((const float4*)ss)[32 + q];
    v.x = gelu_f(v.x * sc.x + sh.x);
    v.y = gelu_f(v.y * sc.y + sh.y);
    v.z = gelu_f(v.z * sc.z + sh.z);
    v.w = gelu_f(v.w * sc.w + sh.w);
    ((float4*)h)[idx] = v;
}

// ---------------- global mean pool: chunked sum + finalize ----------------
__global__ __launch_bounds__(128) void pool_sum_k(const float* __restrict__ h,
                                                  const int* __restrict__ batch,
                                                  float* __restrict__ sums) {
    int r0 = blockIdx.x * POOL_CHUNK;
    int r1 = min(r0 + POOL_CHUNK, NN);
    if (r0 >= NN) return;
    int c = threadIdx.x;
    float acc = 0.f;
    int g = batch[r0];
    for (int r = r0; r < r1; ++r) {
        int gr = batch[r];
        if (gr != g) {
            atomicAdd(&sums[g * 128 + c], acc);
            acc = 0.f;
            g = gr;
        }
        acc += h[(size_t)r * 128 + c];
    }
    atomicAdd(&sums[g * 128 + c], acc);
}

__device__ __forceinline__ int lower_bound_dev(const int* __restrict__ a, int n, int key) {
    int lo = 0, hi = n;
    while (lo < hi) {
        int mid = (lo + hi) >> 1;
        if (a[mid] < key) lo = mid + 1; else hi = mid;
    }
    return lo;
}

__global__ __launch_bounds__(128) void pool_div_k(const float* __restrict__ sums,
                                                  const int* __restrict__ batch,
                                                  float* __restrict__ pooled) {
    int g = blockIdx.x;
    int a = lower_bound_dev(batch, NN, g);
    int b = lower_bound_dev(batch, NN, g + 1);
    float inv = 1.0f / fmaxf((float)(b - a), 1.0f);
    int c = threadIdx.x;
    pooled[g * 128 + c] = sums[g * 128 + c] * inv;
}

// ---------------- MLP head ----------------
__global__ __launch_bounds__(128) void head_k(const float* __restrict__ pooled,
                                              const float* __restrict__ W0, const float* __restrict__ b0,
                                              const float* __restrict__ W1, const float* __restrict__ b1,
                                              const float* __restrict__ W2, const float* __restrict__ b2,
                                              float* __restrict__ out) {
    __shared__ float r0[128], r1[128];
    int g = blockIdx.x, t = threadIdx.x;
    r0[t] = pooled[g * 128 + t];
    __syncthreads();
    float acc = b0[t];
    for (int k = 0; k < 128; ++k) acc += r0[k] * W0[k * 128 + t];
    r1[t] = gelu_f(acc);
    __syncthreads();
    acc = b1[t];
    for (int k = 0; k < 128; ++k) acc += r1[k] * W1[k * 128 + t];
    float y = gelu_f(acc);
    __syncthreads();
    r0[t] = y;
    __syncthreads();
    if (t < 10) {
        acc = b2[t];
        for (int k = 0; k < 128; ++k) acc += r0[k] * W2[k * 10 + t];
        out[g * 10 + t] = acc;
    }
}

extern "C" void kernel_launch(void* const* d_in, const int* in_sizes, int n_in,
                              void* d_out, int out_size, void* d_ws, size_t ws_size,
                              hipStream_t stream) {
    const float* x      = (const float*)d_in[0];
    const int*   ei     = (const int*)d_in[1];
    const int*   batch  = (const int*)d_in[2];
    const float* Wb0    = (const float*)d_in[4];
    const float* bb0    = (const float*)d_in[5];
    const float* gb0    = (const float*)d_in[6];
    const float* betab0 = (const float*)d_in[7];
    const float* Wb1    = (const float*)d_in[8];
    const float* bb1    = (const float*)d_in[9];
    const float* Wa0    = (const float*)d_in[10];
    const float* ba0    = (const float*)d_in[11];
    const float* ga0    = (const float*)d_in[12];
    const float* bea0   = (const float*)d_in[13];
    const float* Wa1    = (const float*)d_in[14];
    const float* ba1    = (const float*)d_in[15];
    const float* ga1    = (const float*)d_in[16];
    const float* bea1   = (const float*)d_in[17];
    const float* Wa2    = (const float*)d_in[18];
    const float* ba2    = (const float*)d_in[19];
    const float* Wh0    = (const float*)d_in[20];
    const float* bh0    = (const float*)d_in[21];
    const float* Wh1    = (const float*)d_in[22];
    const float* bh1    = (const float*)d_in[23];
    const float* Wh2    = (const float*)d_in[24];
    const float* bh2    = (const float*)d_in[25];
    float* out = (float*)d_out;

    char* ws = (char*)d_ws;
    float* bufA    = (float*)ws;                       ws += (size_t)NN * CH * 4;
    float* bufB    = (float*)ws;                       ws += (size_t)NN * CH * 4;
    float* bufC    = (float*)ws;                       ws += (size_t)NN * CH * 4;
    int*   cnt     = (int*)ws;                         ws += (size_t)NN * 4;
    float* dinv    = (float*)ws;                       ws += (size_t)NN * 4;
    int*   row_ptr = (int*)ws;                         ws += (size_t)(NN + 1) * 4;
    int*   fill    = (int*)ws;                         ws += (size_t)NN * 4;
    int*   csr_src = (int*)ws;                         ws += (size_t)NE * 4;
    float* csr_w   = (float*)ws;                       ws += (size_t)NE * 4;
    float* bnss    = (float*)ws;                       ws += 256 * 4;
    float* ssbuf   = (float*)ws;                       ws += 256 * 4;
    float* psum    = (float*)ws;                       ws += (size_t)NG * CH * 4;
    float* pooled  = (float*)ws;                       ws += (size_t)NG * CH * 4;

    // CSR build
    hipMemsetAsync(cnt, 0, NN * sizeof(int), stream);
    hist_k<<<(NE + 255) / 256, 256, 0, stream>>>(ei, cnt);
    dinv_k<<<(NN + 255) / 256, 256, 0, stream>>>(cnt, dinv);
    scan_k<<<1, 1024, 0, stream>>>(cnt, row_ptr, fill);
    scatter_k<<<(NE + 255) / 256, 256, 0, stream>>>(ei, dinv, row_ptr, fill, csr_src, csr_w);

    auto conv = [&](const float* in, const float* W, const float* b, float* o) {
        gemm_k<<<(NN + 31) / 32, 256, 0, stream>>>(in, W, bufA);
        csr_agg_k<<<(NN * 64 + 255) / 256, 256, 0, stream>>>(row_ptr, csr_src, csr_w, bufA, b, dinv, o);
    };
    auto bn_gelu = [&](float* h, const float* g, const float* beta) {
        hipMemsetAsync(bnss, 0, 256 * sizeof(float), stream);
        bn_stats_k<<<(NN + 127) / 128, 256, 0, stream>>>(h, bnss);
        bn_finalize_k<<<1, 128, 0, stream>>>(bnss, g, beta, ssbuf);
        bn_apply_gelu_k<<<(NN * 32) / 256, 256, 0, stream>>>(h, ssbuf);
    };

    conv(x, Wb0, bb0, bufB);
    bn_gelu(bufB, gb0, betab0);
    conv(bufB, Wb1, bb1, bufC);
    conv(bufC, Wa0, ba0, bufB);
    bn_gelu(bufB, ga0, bea0);
    conv(bufB, Wa1, ba1, bufC);
    bn_gelu(bufC, ga1, bea1);
    conv(bufC, Wa2, ba2, bufB);

    hipMemsetAsync(psum, 0, NG * CH * sizeof(float), stream);
    pool_sum_k<<<(NN + POOL_CHUNK - 1) / POOL_CHUNK, 128, 0, stream>>>(bufB, batch, psum);
    pool_div_k<<<NG, 128, 0, stream>>>(psum, batch, pooled);
    head_k<<<NG, 128, 0, stream>>>(pooled, Wh0, bh0, Wh1, bh1, Wh2, bh2, out);
}

// Round 4
// 886.214 us; speedup vs baseline: 8.3836x; 1.1282x over previous
//
#include <hip/hip_runtime.h>
#include <math.h>

#define NN 50000
#define NE 800000
#define CH 128
#define NG 64
#define BN_EPS 1e-5f
#define POOL_CHUNK 64
#define SCAN_B 256
#define NBLK ((NN + SCAN_B - 1) / SCAN_B)   // 196

__device__ __forceinline__ float gelu_f(float x) {
    return 0.5f * x * (1.0f + erff(x * 0.70710678118654752440f));
}

// ---------------- degree histogram (int) ----------------
__global__ __launch_bounds__(256) void hist_k(const int* __restrict__ ei, int* __restrict__ cnt) {
    int e = blockIdx.x * 256 + threadIdx.x;
    if (e < NE) atomicAdd(&cnt[ei[NE + e]], 1);
}

__global__ __launch_bounds__(256) void dinv_k(const int* __restrict__ cnt, float* __restrict__ dinv) {
    int i = blockIdx.x * 256 + threadIdx.x;
    if (i < NN) dinv[i] = rsqrtf((float)cnt[i] + 1.0f);  // +1 = self loop
}

// ---------------- two-level scan ----------------
__global__ __launch_bounds__(256) void blk_sum_k(const int* __restrict__ cnt, int* __restrict__ bsum) {
    __shared__ int sh[256];
    int i = blockIdx.x * 256 + threadIdx.x;
    sh[threadIdx.x] = (i < NN) ? cnt[i] : 0;
    __syncthreads();
    for (int off = 128; off > 0; off >>= 1) {
        if (threadIdx.x < off) sh[threadIdx.x] += sh[threadIdx.x + off];
        __syncthreads();
    }
    if (threadIdx.x == 0) bsum[blockIdx.x] = sh[0];
}

__global__ __launch_bounds__(256) void blk_scan_k(const int* __restrict__ bsum,
                                                  int* __restrict__ boff,
                                                  int* __restrict__ row_ptr) {
    __shared__ int sh[256];
    int t = threadIdx.x;
    int v = (t < NBLK) ? bsum[t] : 0;
    sh[t] = v;
    __syncthreads();
    for (int off = 1; off < 256; off <<= 1) {
        int a = (t >= off) ? sh[t - off] : 0;
        __syncthreads();
        sh[t] += a;
        __syncthreads();
    }
    if (t < NBLK) boff[t] = sh[t] - v;     // exclusive block offset
    if (t == 255) row_ptr[NN] = sh[255];   // total (= NE)
}

__global__ __launch_bounds__(256) void emit_k(const int* __restrict__ cnt,
                                              const int* __restrict__ boff,
                                              int* __restrict__ row_ptr,
                                              int* __restrict__ fill) {
    __shared__ int sh[256];
    int i = blockIdx.x * 256 + threadIdx.x;
    int t = threadIdx.x;
    int v = (i < NN) ? cnt[i] : 0;
    sh[t] = v;
    __syncthreads();
    for (int off = 1; off < 256; off <<= 1) {
        int a = (t >= off) ? sh[t - off] : 0;
        __syncthreads();
        sh[t] += a;
        __syncthreads();
    }
    if (i < NN) {
        row_ptr[i] = boff[blockIdx.x] + sh[t] - v;
        fill[i] = 0;
    }
}

// ---------------- scatter edges into CSR slots ----------------
__global__ __launch_bounds__(256) void scatter_k(const int* __restrict__ ei,
                                                 const float* __restrict__ dinv,
                                                 const int* __restrict__ row_ptr,
                                                 int* __restrict__ fill,
                                                 int* __restrict__ csr_src,
                                                 float* __restrict__ csr_w) {
    int e = blockIdx.x * 256 + threadIdx.x;
    if (e >= NE) return;
    int s = ei[e];
    int d = ei[NE + e];
    int pos = row_ptr[d] + atomicAdd(&fill[d], 1);
    csr_src[pos] = s;
    csr_w[pos] = dinv[s] * dinv[d];
}

// ---------------- GEMM: out[N,128] = A[N,128] @ W[128,128] ----------------
__global__ __launch_bounds__(256) void gemm_k(const float* __restrict__ A,
                                              const float* __restrict__ W,
                                              float* __restrict__ out) {
    __shared__ float At[32 * 128];
    const int tid = threadIdx.x;
    const int row0 = blockIdx.x * 32;

    #pragma unroll
    for (int i = 0; i < 4; ++i) {
        int idx = tid + i * 256;
        int r = idx >> 5;
        float4 v = make_float4(0.f, 0.f, 0.f, 0.f);
        if (row0 + r < NN) v = ((const float4*)A)[(size_t)(row0 + r) * 32 + (idx & 31)];
        ((float4*)At)[idx] = v;
    }
    __syncthreads();

    const int c0 = (tid & 63) * 2;
    const int rg = tid >> 6;

    float acc0[8], acc1[8];
    #pragma unroll
    for (int i = 0; i < 8; ++i) { acc0[i] = 0.f; acc1[i] = 0.f; }

    for (int k4 = 0; k4 < 32; ++k4) {
        float2 w0 = *(const float2*)&W[(k4 * 4 + 0) * 128 + c0];
        float2 w1 = *(const float2*)&W[(k4 * 4 + 1) * 128 + c0];
        float2 w2 = *(const float2*)&W[(k4 * 4 + 2) * 128 + c0];
        float2 w3 = *(const float2*)&W[(k4 * 4 + 3) * 128 + c0];
        #pragma unroll
        for (int i = 0; i < 8; ++i) {
            float4 a = *(const float4*)&At[(rg * 8 + i) * 128 + k4 * 4];
            acc0[i] += a.x * w0.x + a.y * w1.x + a.z * w2.x + a.w * w3.x;
            acc1[i] += a.x * w0.y + a.y * w1.y + a.z * w2.y + a.w * w3.y;
        }
    }
    #pragma unroll
    for (int i = 0; i < 8; ++i) {
        int r = row0 + rg * 8 + i;
        if (r < NN) *(float2*)&out[(size_t)r * 128 + c0] = make_float2(acc0[i], acc1[i]);
    }
}

// ---------------- CSR aggregation: one wave per node, fused bias+self-loop ----------------
__global__ __launch_bounds__(256) void csr_agg_k(const int* __restrict__ row_ptr,
                                                 const int* __restrict__ csr_src,
                                                 const float* __restrict__ csr_w,
                                                 const float* __restrict__ hw,
                                                 const float* __restrict__ bias,
                                                 const float* __restrict__ dinv,
                                                 float* __restrict__ out) {
    int node = (blockIdx.x * 256 + threadIdx.x) >> 6;
    if (node >= NN) return;
    int lane = threadIdx.x & 63;

    const float2* hw2 = (const float2*)hw;
    float di = dinv[node];
    float sw = di * di;
    float2 b = ((const float2*)bias)[lane];
    float2 h = hw2[(size_t)node * 64 + lane];
    float2 acc = make_float2(b.x + h.x * sw, b.y + h.y * sw);

    int j = row_ptr[node];
    int j1 = row_ptr[node + 1];
    for (; j + 1 < j1; j += 2) {
        int s0 = csr_src[j], s1 = csr_src[j + 1];
        float w0 = csr_w[j], w1 = csr_w[j + 1];
        float2 v0 = hw2[(size_t)s0 * 64 + lane];
        float2 v1 = hw2[(size_t)s1 * 64 + lane];
        acc.x += v0.x * w0 + v1.x * w1;
        acc.y += v0.y * w0 + v1.y * w1;
    }
    if (j < j1) {
        int s = csr_src[j];
        float w = csr_w[j];
        float2 v = hw2[(size_t)s * 64 + lane];
        acc.x += v.x * w;
        acc.y += v.y * w;
    }
    ((float2*)out)[(size_t)node * 64 + lane] = acc;
}

// ---------------- batchnorm ----------------
__global__ __launch_bounds__(256) void bn_stats_k(const float* __restrict__ h, float* __restrict__ sums) {
    int c = threadIdx.x & 127;
    int half = threadIdx.x >> 7;
    int r0 = blockIdx.x * 128 + half;
    float s = 0.f, ss = 0.f;
    #pragma unroll 4
    for (int i = 0; i < 64; ++i) {
        int r = r0 + i * 2;
        if (r < NN) {
            float v = h[(size_t)r * 128 + c];
            s += v; ss += v * v;
        }
    }
    __shared__ float sh_s[128], sh_ss[128];
    if (half == 1) { sh_s[c] = s; sh_ss[c] = ss; }
    __syncthreads();
    if (half == 0) {
        atomicAdd(&sums[c], s + sh_s[c]);
        atomicAdd(&sums[128 + c], ss + sh_ss[c]);
    }
}

__global__ __launch_bounds__(128) void bn_finalize_k(const float* __restrict__ sums,
                                                     const float* __restrict__ g,
                                                     const float* __restrict__ beta,
                                                     float* __restrict__ ss) {
    int c = threadIdx.x;
    float mean = sums[c] * (1.0f / NN);
    float var = sums[128 + c] * (1.0f / NN) - mean * mean;
    float sc = g[c] * rsqrtf(var + BN_EPS);
    ss[c] = sc;
    ss[128 + c] = beta[c] - mean * sc;
}

__global__ __launch_bounds__(256) void bn_apply_gelu_k(float* __restrict__ h, const float* __restrict__ ss) {
    int idx = blockIdx.x * 256 + threadIdx.x;
    if (idx >= NN * 32) return;
    int q = idx & 31;
    float4 v = ((float4*)h)[idx];
    float4 sc = ((const float4*)ss)[q];
    float4 sh = ((const float4*)ss)[32 + q];
    v.x = gelu_f(v.x * sc.x + sh.x);
    v.y = gelu_f(v.y * sc.y + sh.y);
    v.z = gelu_f(v.z * sc.z + sh.z);
    v.w = gelu_f(v.w * sc.w + sh.w);
    ((float4*)h)[idx] = v;
}

// ---------------- global mean pool: chunked sum + finalize ----------------
__global__ __launch_bounds__(128) void pool_sum_k(const float* __restrict__ h,
                                                  const int* __restrict__ batch,
                                                  float* __restrict__ sums) {
    int r0 = blockIdx.x * POOL_CHUNK;
    int r1 = min(r0 + POOL_CHUNK, NN);
    if (r0 >= NN) return;
    int c = threadIdx.x;
    float acc = 0.f;
    int g = batch[r0];
    for (int r = r0; r < r1; ++r) {
        int gr = batch[r];
        if (gr != g) {
            atomicAdd(&sums[g * 128 + c], acc);
            acc = 0.f;
            g = gr;
        }
        acc += h[(size_t)r * 128 + c];
    }
    atomicAdd(&sums[g * 128 + c], acc);
}

__device__ __forceinline__ int lower_bound_dev(const int* __restrict__ a, int n, int key) {
    int lo = 0, hi = n;
    while (lo < hi) {
        int mid = (lo + hi) >> 1;
        if (a[mid] < key) lo = mid + 1; else hi = mid;
    }
    return lo;
}

__global__ __launch_bounds__(128) void pool_div_k(const float* __restrict__ sums,
                                                  const int* __restrict__ batch,
                                                  float* __restrict__ pooled) {
    int g = blockIdx.x;
    int a = lower_bound_dev(batch, NN, g);
    int b = lower_bound_dev(batch, NN, g + 1);
    float inv = 1.0f / fmaxf((float)(b - a), 1.0f);
    int c = threadIdx.x;
    pooled[g * 128 + c] = sums[g * 128 + c] * inv;
}

// ---------------- MLP head ----------------
__global__ __launch_bounds__(128) void head_k(const float* __restrict__ pooled,
                                              const float* __restrict__ W0, const float* __restrict__ b0,
                                              const float* __restrict__ W1, const float* __restrict__ b1,
                                              const float* __restrict__ W2, const float* __restrict__ b2,
                                              float* __restrict__ out) {
    __shared__ float r0[128], r1[128];
    int g = blockIdx.x, t = threadIdx.x;
    r0[t] = pooled[g * 128 + t];
    __syncthreads();
    float acc = b0[t];
    for (int k = 0; k < 128; ++k) acc += r0[k] * W0[k * 128 + t];
    r1[t] = gelu_f(acc);
    __syncthreads();
    acc = b1[t];
    for (int k = 0; k < 128; ++k) acc += r1[k] * W1[k * 128 + t];
    float y = gelu_f(acc);
    __syncthreads();
    r0[t] = y;
    __syncthreads();
    if (t < 10) {
        acc = b2[t];
        for (int k = 0; k < 128; ++k) acc += r0[k] * W2[k * 10 + t];
        out[g * 10 + t] = acc;
    }
}

extern "C" void kernel_launch(void* const* d_in, const int* in_sizes, int n_in,
                              void* d_out, int out_size, void* d_ws, size_t ws_size,
                              hipStream_t stream) {
    const float* x      = (const float*)d_in[0];
    const int*   ei     = (const int*)d_in[1];
    const int*   batch  = (const int*)d_in[2];
    const float* Wb0    = (const float*)d_in[4];
    const float* bb0    = (const float*)d_in[5];
    const float* gb0    = (const float*)d_in[6];
    const float* betab0 = (const float*)d_in[7];
    const float* Wb1    = (const float*)d_in[8];
    const float* bb1    = (const float*)d_in[9];
    const float* Wa0    = (const float*)d_in[10];
    const float* ba0    = (const float*)d_in[11];
    const float* ga0    = (const float*)d_in[12];
    const float* bea0   = (const float*)d_in[13];
    const float* Wa1    = (const float*)d_in[14];
    const float* ba1    = (const float*)d_in[15];
    const float* ga1    = (const float*)d_in[16];
    const float* bea1   = (const float*)d_in[17];
    const float* Wa2    = (const float*)d_in[18];
    const float* ba2    = (const float*)d_in[19];
    const float* Wh0    = (const float*)d_in[20];
    const float* bh0    = (const float*)d_in[21];
    const float* Wh1    = (const float*)d_in[22];
    const float* bh1    = (const float*)d_in[23];
    const float* Wh2    = (const float*)d_in[24];
    const float* bh2    = (const float*)d_in[25];
    float* out = (float*)d_out;

    char* ws = (char*)d_ws;
    float* bufA    = (float*)ws;                       ws += (size_t)NN * CH * 4;
    float* bufB    = (float*)ws;                       ws += (size_t)NN * CH * 4;
    float* bufC    = (float*)ws;                       ws += (size_t)NN * CH * 4;
    int*   cnt     = (int*)ws;                         ws += (size_t)NN * 4;
    float* dinv    = (float*)ws;                       ws += (size_t)NN * 4;
    int*   row_ptr = (int*)ws;                         ws += (size_t)(NN + 1) * 4;
    int*   fill    = (int*)ws;                         ws += (size_t)NN * 4;
    int*   csr_src = (int*)ws;                         ws += (size_t)NE * 4;
    float* csr_w   = (float*)ws;                       ws += (size_t)NE * 4;
    int*   bsum    = (int*)ws;                         ws += 256 * 4;
    int*   boff    = (int*)ws;                         ws += 256 * 4;
    float* bnss    = (float*)ws;                       ws += 256 * 4;
    float* ssbuf   = (float*)ws;                       ws += 256 * 4;
    float* psum    = (float*)ws;                       ws += (size_t)NG * CH * 4;
    float* pooled  = (float*)ws;                       ws += (size_t)NG * CH * 4;

    // CSR build
    hipMemsetAsync(cnt, 0, NN * sizeof(int), stream);
    hist_k<<<(NE + 255) / 256, 256, 0, stream>>>(ei, cnt);
    dinv_k<<<(NN + 255) / 256, 256, 0, stream>>>(cnt, dinv);
    blk_sum_k<<<NBLK, 256, 0, stream>>>(cnt, bsum);
    blk_scan_k<<<1, 256, 0, stream>>>(bsum, boff, row_ptr);
    emit_k<<<NBLK, 256, 0, stream>>>(cnt, boff, row_ptr, fill);
    scatter_k<<<(NE + 255) / 256, 256, 0, stream>>>(ei, dinv, row_ptr, fill, csr_src, csr_w);

    auto conv = [&](const float* in, const float* W, const float* b, float* o) {
        gemm_k<<<(NN + 31) / 32, 256, 0, stream>>>(in, W, bufA);
        csr_agg_k<<<(NN * 64 + 255) / 256, 256, 0, stream>>>(row_ptr, csr_src, csr_w, bufA, b, dinv, o);
    };
    auto bn_gelu = [&](float* h, const float* g, const float* beta) {
        hipMemsetAsync(bnss, 0, 256 * sizeof(float), stream);
        bn_stats_k<<<(NN + 127) / 128, 256, 0, stream>>>(h, bnss);
        bn_finalize_k<<<1, 128, 0, stream>>>(bnss, g, beta, ssbuf);
        bn_apply_gelu_k<<<(NN * 32) / 256, 256, 0, stream>>>(h, ssbuf);
    };

    conv(x, Wb0, bb0, bufB);
    bn_gelu(bufB, gb0, betab0);
    conv(bufB, Wb1, bb1, bufC);
    conv(bufC, Wa0, ba0, bufB);
    bn_gelu(bufB, ga0, bea0);
    conv(bufB, Wa1, ba1, bufC);
    bn_gelu(bufC, ga1, bea1);
    conv(bufC, Wa2, ba2, bufB);

    hipMemsetAsync(psum, 0, NG * CH * sizeof(float), stream);
    pool_sum_k<<<(NN + POOL_CHUNK - 1) / POOL_CHUNK, 128, 0, stream>>>(bufB, batch, psum);
    pool_div_k<<<NG, 128, 0, stream>>>(psum, batch, pooled);
    head_k<<<NG, 128, 0, stream>>>(pooled, Wh0, bh0, Wh1, bh1, Wh2, bh2, out);
}

// Round 5
// 736.696 us; speedup vs baseline: 10.0851x; 1.2030x over previous
//
#include <hip/hip_runtime.h>
#include <math.h>

#define NN 50000
#define NE 800000
#define CH 128
#define NG 64
#define BN_EPS 1e-5f
#define POOL_CHUNK 64
#define SCAN_B 256
#define NBLK ((NN + SCAN_B - 1) / SCAN_B)   // 196

__device__ __forceinline__ float gelu_f(float x) {
    return 0.5f * x * (1.0f + erff(x * 0.70710678118654752440f));
}

// bf16 helpers (RNE pack, bit-exact unpack)
__device__ __forceinline__ unsigned int f2bf(float f) {
    unsigned int u = __float_as_uint(f);
    return (u + 0x7FFFu + ((u >> 16) & 1u)) >> 16;
}
__device__ __forceinline__ unsigned int pack_bf2(float lo, float hi) {
    return (f2bf(hi) << 16) | f2bf(lo);
}
__device__ __forceinline__ float bf_lo(unsigned int v) { return __uint_as_float(v << 16); }
__device__ __forceinline__ float bf_hi(unsigned int v) { return __uint_as_float(v & 0xFFFF0000u); }

// ---------------- degree histogram (int) ----------------
__global__ __launch_bounds__(256) void hist_k(const int* __restrict__ ei, int* __restrict__ cnt) {
    int e = blockIdx.x * 256 + threadIdx.x;
    if (e < NE) atomicAdd(&cnt[ei[NE + e]], 1);
}

__global__ __launch_bounds__(256) void dinv_k(const int* __restrict__ cnt, float* __restrict__ dinv) {
    int i = blockIdx.x * 256 + threadIdx.x;
    if (i < NN) dinv[i] = rsqrtf((float)cnt[i] + 1.0f);  // +1 = self loop
}

// ---------------- two-level scan ----------------
__global__ __launch_bounds__(256) void blk_sum_k(const int* __restrict__ cnt, int* __restrict__ bsum) {
    __shared__ int sh[256];
    int i = blockIdx.x * 256 + threadIdx.x;
    sh[threadIdx.x] = (i < NN) ? cnt[i] : 0;
    __syncthreads();
    for (int off = 128; off > 0; off >>= 1) {
        if (threadIdx.x < off) sh[threadIdx.x] += sh[threadIdx.x + off];
        __syncthreads();
    }
    if (threadIdx.x == 0) bsum[blockIdx.x] = sh[0];
}

__global__ __launch_bounds__(256) void blk_scan_k(const int* __restrict__ bsum,
                                                  int* __restrict__ boff,
                                                  int* __restrict__ row_ptr) {
    __shared__ int sh[256];
    int t = threadIdx.x;
    int v = (t < NBLK) ? bsum[t] : 0;
    sh[t] = v;
    __syncthreads();
    for (int off = 1; off < 256; off <<= 1) {
        int a = (t >= off) ? sh[t - off] : 0;
        __syncthreads();
        sh[t] += a;
        __syncthreads();
    }
    if (t < NBLK) boff[t] = sh[t] - v;
    if (t == 255) row_ptr[NN] = sh[255];
}

__global__ __launch_bounds__(256) void emit_k(const int* __restrict__ cnt,
                                              const int* __restrict__ boff,
                                              int* __restrict__ row_ptr,
                                              int* __restrict__ fill) {
    __shared__ int sh[256];
    int i = blockIdx.x * 256 + threadIdx.x;
    int t = threadIdx.x;
    int v = (i < NN) ? cnt[i] : 0;
    sh[t] = v;
    __syncthreads();
    for (int off = 1; off < 256; off <<= 1) {
        int a = (t >= off) ? sh[t - off] : 0;
        __syncthreads();
        sh[t] += a;
        __syncthreads();
    }
    if (i < NN) {
        row_ptr[i] = boff[blockIdx.x] + sh[t] - v;
        fill[i] = 0;
    }
}

// ---------------- scatter edges into CSR slots ----------------
__global__ __launch_bounds__(256) void scatter_k(const int* __restrict__ ei,
                                                 const float* __restrict__ dinv,
                                                 const int* __restrict__ row_ptr,
                                                 int* __restrict__ fill,
                                                 int* __restrict__ csr_src,
                                                 float* __restrict__ csr_w) {
    int e = blockIdx.x * 256 + threadIdx.x;
    if (e >= NE) return;
    int s = ei[e];
    int d = ei[NE + e];
    int pos = row_ptr[d] + atomicAdd(&fill[d], 1);
    csr_src[pos] = s;
    csr_w[pos] = dinv[s] * dinv[d];
}

// ---------------- GEMM: hw16[N,128](bf16x2) = act(A[N,128]) @ W[128,128] ----------------
// If ss != null, A is transformed on load: gelu(a*sc + sh)  (fused BN+GELU).
__global__ __launch_bounds__(256) void gemm_k(const float* __restrict__ A,
                                              const float* __restrict__ W,
                                              const float* __restrict__ ss,   // scale[128], shift[128] or null
                                              unsigned int* __restrict__ hw16) {
    __shared__ float At[32 * 128];
    const int tid = threadIdx.x;
    const int row0 = blockIdx.x * 32;

    #pragma unroll
    for (int i = 0; i < 4; ++i) {
        int idx = tid + i * 256;
        int r = idx >> 5;
        int q = idx & 31;
        float4 v = make_float4(0.f, 0.f, 0.f, 0.f);
        if (row0 + r < NN) {
            v = ((const float4*)A)[(size_t)(row0 + r) * 32 + q];
            if (ss) {
                float4 sc = ((const float4*)ss)[q];
                float4 sh = ((const float4*)ss)[32 + q];
                v.x = gelu_f(v.x * sc.x + sh.x);
                v.y = gelu_f(v.y * sc.y + sh.y);
                v.z = gelu_f(v.z * sc.z + sh.z);
                v.w = gelu_f(v.w * sc.w + sh.w);
            }
        }
        ((float4*)At)[idx] = v;
    }
    __syncthreads();

    const int c0 = (tid & 63) * 2;
    const int rg = tid >> 6;

    float acc0[8], acc1[8];
    #pragma unroll
    for (int i = 0; i < 8; ++i) { acc0[i] = 0.f; acc1[i] = 0.f; }

    for (int k4 = 0; k4 < 32; ++k4) {
        float2 w0 = *(const float2*)&W[(k4 * 4 + 0) * 128 + c0];
        float2 w1 = *(const float2*)&W[(k4 * 4 + 1) * 128 + c0];
        float2 w2 = *(const float2*)&W[(k4 * 4 + 2) * 128 + c0];
        float2 w3 = *(const float2*)&W[(k4 * 4 + 3) * 128 + c0];
        #pragma unroll
        for (int i = 0; i < 8; ++i) {
            float4 a = *(const float4*)&At[(rg * 8 + i) * 128 + k4 * 4];
            acc0[i] += a.x * w0.x + a.y * w1.x + a.z * w2.x + a.w * w3.x;
            acc1[i] += a.x * w0.y + a.y * w1.y + a.z * w2.y + a.w * w3.y;
        }
    }
    #pragma unroll
    for (int i = 0; i < 8; ++i) {
        int r = row0 + rg * 8 + i;
        if (r < NN) hw16[(size_t)r * 64 + (c0 >> 1)] = pack_bf2(acc0[i], acc1[i]);
    }
}

// ---------------- CSR aggregation: one wave per node, bf16 gather, fp32 accumulate ----------------
__global__ __launch_bounds__(256) void csr_agg_k(const int* __restrict__ row_ptr,
                                                 const int* __restrict__ csr_src,
                                                 const float* __restrict__ csr_w,
                                                 const unsigned int* __restrict__ hw16,
                                                 const float* __restrict__ bias,
                                                 const float* __restrict__ dinv,
                                                 float* __restrict__ out) {
    int node = (blockIdx.x * 256 + threadIdx.x) >> 6;
    if (node >= NN) return;
    int lane = threadIdx.x & 63;

    float di = dinv[node];
    float sw = di * di;
    float2 b = ((const float2*)bias)[lane];
    unsigned int hs = hw16[(size_t)node * 64 + lane];
    float accx = b.x + bf_lo(hs) * sw;
    float accy = b.y + bf_hi(hs) * sw;
    float acc2x = 0.f, acc2y = 0.f;

    int j = row_ptr[node];
    int j1 = row_ptr[node + 1];
    for (; j + 3 < j1; j += 4) {
        int s0 = csr_src[j + 0], s1 = csr_src[j + 1];
        int s2 = csr_src[j + 2], s3 = csr_src[j + 3];
        float w0 = csr_w[j + 0], w1 = csr_w[j + 1];
        float w2 = csr_w[j + 2], w3 = csr_w[j + 3];
        unsigned int v0 = hw16[(size_t)s0 * 64 + lane];
        unsigned int v1 = hw16[(size_t)s1 * 64 + lane];
        unsigned int v2 = hw16[(size_t)s2 * 64 + lane];
        unsigned int v3 = hw16[(size_t)s3 * 64 + lane];
        accx  += bf_lo(v0) * w0 + bf_lo(v1) * w1;
        accy  += bf_hi(v0) * w0 + bf_hi(v1) * w1;
        acc2x += bf_lo(v2) * w2 + bf_lo(v3) * w3;
        acc2y += bf_hi(v2) * w2 + bf_hi(v3) * w3;
    }
    for (; j < j1; ++j) {
        int s = csr_src[j];
        float w = csr_w[j];
        unsigned int v = hw16[(size_t)s * 64 + lane];
        accx += bf_lo(v) * w;
        accy += bf_hi(v) * w;
    }
    ((float2*)out)[(size_t)node * 64 + lane] = make_float2(accx + acc2x, accy + acc2y);
}

// ---------------- batchnorm stats ----------------
__global__ __launch_bounds__(256) void bn_stats_k(const float* __restrict__ h, float* __restrict__ sums) {
    int c = threadIdx.x & 127;
    int half = threadIdx.x >> 7;
    int r0 = blockIdx.x * 128 + half;
    float s = 0.f, ss = 0.f;
    #pragma unroll 4
    for (int i = 0; i < 64; ++i) {
        int r = r0 + i * 2;
        if (r < NN) {
            float v = h[(size_t)r * 128 + c];
            s += v; ss += v * v;
        }
    }
    __shared__ float sh_s[128], sh_ss[128];
    if (half == 1) { sh_s[c] = s; sh_ss[c] = ss; }
    __syncthreads();
    if (half == 0) {
        atomicAdd(&sums[c], s + sh_s[c]);
        atomicAdd(&sums[128 + c], ss + sh_ss[c]);
    }
}

__global__ __launch_bounds__(128) void bn_finalize_k(const float* __restrict__ sums,
                                                     const float* __restrict__ g,
                                                     const float* __restrict__ beta,
                                                     float* __restrict__ ss) {
    int c = threadIdx.x;
    float mean = sums[c] * (1.0f / NN);
    float var = sums[128 + c] * (1.0f / NN) - mean * mean;
    float sc = g[c] * rsqrtf(var + BN_EPS);
    ss[c] = sc;
    ss[128 + c] = beta[c] - mean * sc;
}

// ---------------- global mean pool: chunked sum + finalize ----------------
__global__ __launch_bounds__(128) void pool_sum_k(const float* __restrict__ h,
                                                  const int* __restrict__ batch,
                                                  float* __restrict__ sums) {
    int r0 = blockIdx.x * POOL_CHUNK;
    int r1 = min(r0 + POOL_CHUNK, NN);
    if (r0 >= NN) return;
    int c = threadIdx.x;
    float acc = 0.f;
    int g = batch[r0];
    for (int r = r0; r < r1; ++r) {
        int gr = batch[r];
        if (gr != g) {
            atomicAdd(&sums[g * 128 + c], acc);
            acc = 0.f;
            g = gr;
        }
        acc += h[(size_t)r * 128 + c];
    }
    atomicAdd(&sums[g * 128 + c], acc);
}

__device__ __forceinline__ int lower_bound_dev(const int* __restrict__ a, int n, int key) {
    int lo = 0, hi = n;
    while (lo < hi) {
        int mid = (lo + hi) >> 1;
        if (a[mid] < key) lo = mid + 1; else hi = mid;
    }
    return lo;
}

__global__ __launch_bounds__(128) void pool_div_k(const float* __restrict__ sums,
                                                  const int* __restrict__ batch,
                                                  float* __restrict__ pooled) {
    int g = blockIdx.x;
    int a = lower_bound_dev(batch, NN, g);
    int b = lower_bound_dev(batch, NN, g + 1);
    float inv = 1.0f / fmaxf((float)(b - a), 1.0f);
    int c = threadIdx.x;
    pooled[g * 128 + c] = sums[g * 128 + c] * inv;
}

// ---------------- MLP head ----------------
__global__ __launch_bounds__(128) void head_k(const float* __restrict__ pooled,
                                              const float* __restrict__ W0, const float* __restrict__ b0,
                                              const float* __restrict__ W1, const float* __restrict__ b1,
                                              const float* __restrict__ W2, const float* __restrict__ b2,
                                              float* __restrict__ out) {
    __shared__ float r0[128], r1[128];
    int g = blockIdx.x, t = threadIdx.x;
    r0[t] = pooled[g * 128 + t];
    __syncthreads();
    float acc = b0[t];
    for (int k = 0; k < 128; ++k) acc += r0[k] * W0[k * 128 + t];
    r1[t] = gelu_f(acc);
    __syncthreads();
    acc = b1[t];
    for (int k = 0; k < 128; ++k) acc += r1[k] * W1[k * 128 + t];
    float y = gelu_f(acc);
    __syncthreads();
    r0[t] = y;
    __syncthreads();
    if (t < 10) {
        acc = b2[t];
        for (int k = 0; k < 128; ++k) acc += r0[k] * W2[k * 10 + t];
        out[g * 10 + t] = acc;
    }
}

extern "C" void kernel_launch(void* const* d_in, const int* in_sizes, int n_in,
                              void* d_out, int out_size, void* d_ws, size_t ws_size,
                              hipStream_t stream) {
    const float* x      = (const float*)d_in[0];
    const int*   ei     = (const int*)d_in[1];
    const int*   batch  = (const int*)d_in[2];
    const float* Wb0    = (const float*)d_in[4];
    const float* bb0    = (const float*)d_in[5];
    const float* gb0    = (const float*)d_in[6];
    const float* betab0 = (const float*)d_in[7];
    const float* Wb1    = (const float*)d_in[8];
    const float* bb1    = (const float*)d_in[9];
    const float* Wa0    = (const float*)d_in[10];
    const float* ba0    = (const float*)d_in[11];
    const float* ga0    = (const float*)d_in[12];
    const float* bea0   = (const float*)d_in[13];
    const float* Wa1    = (const float*)d_in[14];
    const float* ba1    = (const float*)d_in[15];
    const float* ga1    = (const float*)d_in[16];
    const float* bea1   = (const float*)d_in[17];
    const float* Wa2    = (const float*)d_in[18];
    const float* ba2    = (const float*)d_in[19];
    const float* Wh0    = (const float*)d_in[20];
    const float* bh0    = (const float*)d_in[21];
    const float* Wh1    = (const float*)d_in[22];
    const float* bh1    = (const float*)d_in[23];
    const float* Wh2    = (const float*)d_in[24];
    const float* bh2    = (const float*)d_in[25];
    float* out = (float*)d_out;

    char* ws = (char*)d_ws;
    unsigned int* hw16 = (unsigned int*)ws;            ws += (size_t)NN * 64 * 4;   // bf16x2
    float* bufB    = (float*)ws;                       ws += (size_t)NN * CH * 4;
    float* bufC    = (float*)ws;                       ws += (size_t)NN * CH * 4;
    int*   cnt     = (int*)ws;                         ws += (size_t)NN * 4;
    float* dinv    = (float*)ws;                       ws += (size_t)NN * 4;
    int*   row_ptr = (int*)ws;                         ws += (size_t)(NN + 1) * 4;
    int*   fill    = (int*)ws;                         ws += (size_t)NN * 4;
    int*   csr_src = (int*)ws;                         ws += (size_t)NE * 4;
    float* csr_w   = (float*)ws;                       ws += (size_t)NE * 4;
    int*   bsum    = (int*)ws;                         ws += 256 * 4;
    int*   boff    = (int*)ws;                         ws += 256 * 4;
    float* bnss    = (float*)ws;                       ws += 256 * 4;
    float* ssbuf   = (float*)ws;                       ws += 256 * 4;
    float* psum    = (float*)ws;                       ws += (size_t)NG * CH * 4;
    float* pooled  = (float*)ws;                       ws += (size_t)NG * CH * 4;

    // CSR build
    hipMemsetAsync(cnt, 0, NN * sizeof(int), stream);
    hist_k<<<(NE + 255) / 256, 256, 0, stream>>>(ei, cnt);
    dinv_k<<<(NN + 255) / 256, 256, 0, stream>>>(cnt, dinv);
    blk_sum_k<<<NBLK, 256, 0, stream>>>(cnt, bsum);
    blk_scan_k<<<1, 256, 0, stream>>>(bsum, boff, row_ptr);
    emit_k<<<NBLK, 256, 0, stream>>>(cnt, boff, row_ptr, fill);
    scatter_k<<<(NE + 255) / 256, 256, 0, stream>>>(ei, dinv, row_ptr, fill, csr_src, csr_w);

    auto conv = [&](const float* in, const float* W, const float* b, const float* ss, float* o) {
        gemm_k<<<(NN + 31) / 32, 256, 0, stream>>>(in, W, ss, hw16);
        csr_agg_k<<<(NN * 64 + 255) / 256, 256, 0, stream>>>(row_ptr, csr_src, csr_w, hw16, b, dinv, o);
    };
    auto bn_stats = [&](const float* h, const float* g, const float* beta) {
        hipMemsetAsync(bnss, 0, 256 * sizeof(float), stream);
        bn_stats_k<<<(NN + 127) / 128, 256, 0, stream>>>(h, bnss);
        bn_finalize_k<<<1, 128, 0, stream>>>(bnss, g, beta, ssbuf);
    };

    conv(x, Wb0, bb0, nullptr, bufB);           // conv b0
    bn_stats(bufB, gb0, betab0);                // stats of pre-BN h; apply fused into next gemm
    conv(bufB, Wb1, bb1, ssbuf, bufC);          // conv b1 (A-load: gelu(bn(h)))
    conv(bufC, Wa0, ba0, nullptr, bufB);        // conv a0
    bn_stats(bufB, ga0, bea0);
    conv(bufB, Wa1, ba1, ssbuf, bufC);          // conv a1
    bn_stats(bufC, ga1, bea1);
    conv(bufC, Wa2, ba2, ssbuf, bufB);          // conv a2

    hipMemsetAsync(psum, 0, NG * CH * sizeof(float), stream);
    pool_sum_k<<<(NN + POOL_CHUNK - 1) / POOL_CHUNK, 128, 0, stream>>>(bufB, batch, psum);
    pool_div_k<<<NG, 128, 0, stream>>>(psum, batch, pooled);
    head_k<<<NG, 128, 0, stream>>>(pooled, Wh0, bh0, Wh1, bh1, Wh2, bh2, out);
}

// Round 6
// 639.968 us; speedup vs baseline: 11.6094x; 1.1511x over previous
//
#include <hip/hip_runtime.h>
#include <math.h>

#define NN 50000
#define NE 800000
#define CH 128
#define NG 64
#define BN_EPS 1e-5f
#define POOL_CHUNK 64
#define SCAN_B 256
#define NBLK ((NN + SCAN_B - 1) / SCAN_B)   // 196

typedef short bfrag8 __attribute__((ext_vector_type(8)));   // 8 bf16 (4 VGPRs)
typedef float facc4 __attribute__((ext_vector_type(4)));    // 4 fp32 acc

__device__ __forceinline__ float gelu_f(float x) {
    return 0.5f * x * (1.0f + erff(x * 0.70710678118654752440f));
}

// bf16 helpers (RNE pack, bit-exact unpack)
__device__ __forceinline__ unsigned int f2bf(float f) {
    unsigned int u = __float_as_uint(f);
    return (u + 0x7FFFu + ((u >> 16) & 1u)) >> 16;
}
__device__ __forceinline__ unsigned int pack_bf2(float lo, float hi) {
    return (f2bf(hi) << 16) | f2bf(lo);
}
__device__ __forceinline__ float bf_lo(unsigned int v) { return __uint_as_float(v << 16); }
__device__ __forceinline__ float bf_hi(unsigned int v) { return __uint_as_float(v & 0xFFFF0000u); }

// ---------------- degree histogram (int) ----------------
__global__ __launch_bounds__(256) void hist_k(const int* __restrict__ ei, int* __restrict__ cnt) {
    int e = blockIdx.x * 256 + threadIdx.x;
    if (e < NE) atomicAdd(&cnt[ei[NE + e]], 1);
}

__global__ __launch_bounds__(256) void dinv_k(const int* __restrict__ cnt, float* __restrict__ dinv) {
    int i = blockIdx.x * 256 + threadIdx.x;
    if (i < NN) dinv[i] = rsqrtf((float)cnt[i] + 1.0f);  // +1 = self loop
}

// ---------------- two-level scan ----------------
__global__ __launch_bounds__(256) void blk_sum_k(const int* __restrict__ cnt, int* __restrict__ bsum) {
    __shared__ int sh[256];
    int i = blockIdx.x * 256 + threadIdx.x;
    sh[threadIdx.x] = (i < NN) ? cnt[i] : 0;
    __syncthreads();
    for (int off = 128; off > 0; off >>= 1) {
        if (threadIdx.x < off) sh[threadIdx.x] += sh[threadIdx.x + off];
        __syncthreads();
    }
    if (threadIdx.x == 0) bsum[blockIdx.x] = sh[0];
}

__global__ __launch_bounds__(256) void blk_scan_k(const int* __restrict__ bsum,
                                                  int* __restrict__ boff,
                                                  int* __restrict__ row_ptr) {
    __shared__ int sh[256];
    int t = threadIdx.x;
    int v = (t < NBLK) ? bsum[t] : 0;
    sh[t] = v;
    __syncthreads();
    for (int off = 1; off < 256; off <<= 1) {
        int a = (t >= off) ? sh[t - off] : 0;
        __syncthreads();
        sh[t] += a;
        __syncthreads();
    }
    if (t < NBLK) boff[t] = sh[t] - v;
    if (t == 255) row_ptr[NN] = sh[255];
}

__global__ __launch_bounds__(256) void emit_k(const int* __restrict__ cnt,
                                              const int* __restrict__ boff,
                                              int* __restrict__ row_ptr,
                                              int* __restrict__ fill) {
    __shared__ int sh[256];
    int i = blockIdx.x * 256 + threadIdx.x;
    int t = threadIdx.x;
    int v = (i < NN) ? cnt[i] : 0;
    sh[t] = v;
    __syncthreads();
    for (int off = 1; off < 256; off <<= 1) {
        int a = (t >= off) ? sh[t - off] : 0;
        __syncthreads();
        sh[t] += a;
        __syncthreads();
    }
    if (i < NN) {
        row_ptr[i] = boff[blockIdx.x] + sh[t] - v;
        fill[i] = 0;
    }
}

// ---------------- scatter edges into CSR slots (src only; weights recomputed in agg) ----------------
__global__ __launch_bounds__(256) void scatter_k(const int* __restrict__ ei,
                                                 const int* __restrict__ row_ptr,
                                                 int* __restrict__ fill,
                                                 int* __restrict__ csr_src) {
    int e = blockIdx.x * 256 + threadIdx.x;
    if (e >= NE) return;
    int s = ei[e];
    int d = ei[NE + e];
    int pos = row_ptr[d] + atomicAdd(&fill[d], 1);
    csr_src[pos] = s;
}

// ---------------- W -> bf16 B-fragment-order pack ----------------
// unit u in [0,2048): nt=u>>8, kc=(u>>6)&3, l=u&63; j in [0,8): k=kc*32+(l>>4)*8+j, n=nt*16+(l&15)
__global__ __launch_bounds__(256) void wconv_k(const float* __restrict__ W,
                                               unsigned short* __restrict__ wf) {
    int u = blockIdx.x * 256 + threadIdx.x;   // 0..2047
    int nt = u >> 8, kc = (u >> 6) & 3, l = u & 63;
    int kbase = kc * 32 + (l >> 4) * 8;
    int n = nt * 16 + (l & 15);
    unsigned int p[4];
    #pragma unroll
    for (int jj = 0; jj < 4; ++jj) {
        float a = W[(kbase + 2 * jj) * 128 + n];
        float b = W[(kbase + 2 * jj + 1) * 128 + n];
        p[jj] = pack_bf2(a, b);
    }
    uint4* dst = (uint4*)(wf + (size_t)u * 8);
    *dst = make_uint4(p[0], p[1], p[2], p[3]);
}

// ---------------- MFMA GEMM: out16[N,128](bf16) = act(A[N,128]) @ W[128,128] ----------------
// If ss != null, A is transformed on load: gelu(a*sc + sh)  (fused BN+GELU).
__global__ __launch_bounds__(256) void gemm_k(const float* __restrict__ A,
                                              const unsigned short* __restrict__ wfrag,
                                              const float* __restrict__ ss,
                                              unsigned short* __restrict__ out16) {
    __shared__ unsigned short Alds[8192];    // 64 rows x 128 k, A-fragment order, 16 KB
    __shared__ unsigned short Wlds[16384];   // 128x128, B-fragment order, 32 KB

    const int tid = threadIdx.x;
    const int row0 = blockIdx.x * 64;

    // stage A (fp32 -> optional BN/GELU -> bf16) into fragment order
    #pragma unroll
    for (int i = 0; i < 4; ++i) {
        int linear = tid + i * 256;          // 0..1023
        int r = linear >> 4;                 // row 0..63
        int g = linear & 15;                 // k-group (8 k's)
        float4 v0 = make_float4(0.f, 0.f, 0.f, 0.f);
        float4 v1 = make_float4(0.f, 0.f, 0.f, 0.f);
        if (row0 + r < NN) {
            const float4* src = (const float4*)&A[(size_t)(row0 + r) * 128 + g * 8];
            v0 = src[0];
            v1 = src[1];
            if (ss) {
                float4 sc0 = ((const float4*)ss)[g * 2];
                float4 sh0 = ((const float4*)ss)[32 + g * 2];
                float4 sc1 = ((const float4*)ss)[g * 2 + 1];
                float4 sh1 = ((const float4*)ss)[32 + g * 2 + 1];
                v0.x = gelu_f(v0.x * sc0.x + sh0.x); v0.y = gelu_f(v0.y * sc0.y + sh0.y);
                v0.z = gelu_f(v0.z * sc0.z + sh0.z); v0.w = gelu_f(v0.w * sc0.w + sh0.w);
                v1.x = gelu_f(v1.x * sc1.x + sh1.x); v1.y = gelu_f(v1.y * sc1.y + sh1.y);
                v1.z = gelu_f(v1.z * sc1.z + sh1.z); v1.w = gelu_f(v1.w * sc1.w + sh1.w);
            }
        }
        // fragment unit: w=r>>4, kc=g>>2, quad=g&3, m=r&15 -> ((w*4+kc)*64 + quad*16+m)
        int unit = (((r >> 4) * 4 + (g >> 2)) * 64) + ((g & 3) * 16) + (r & 15);
        uint4* dst = (uint4*)(Alds + (size_t)unit * 8);
        *dst = make_uint4(pack_bf2(v0.x, v0.y), pack_bf2(v0.z, v0.w),
                          pack_bf2(v1.x, v1.y), pack_bf2(v1.z, v1.w));
    }
    // stage W (already fragment-ordered): straight 32 KB copy
    #pragma unroll
    for (int i = 0; i < 8; ++i) {
        int linear = tid + i * 256;          // 0..2047
        ((uint4*)Wlds)[linear] = ((const uint4*)wfrag)[linear];
    }
    __syncthreads();

    const int w = tid >> 6;      // wave 0..3 -> rows 16w..16w+15
    const int l = tid & 63;
    const int quad = l >> 4;
    const int m = l & 15;

    facc4 acc[8];
    #pragma unroll
    for (int nt = 0; nt < 8; ++nt) acc[nt] = (facc4){0.f, 0.f, 0.f, 0.f};

    #pragma unroll
    for (int kc = 0; kc < 4; ++kc) {
        bfrag8 a = *((const bfrag8*)(Alds + ((size_t)((w * 4 + kc) * 64 + l)) * 8));
        #pragma unroll
        for (int nt = 0; nt < 8; ++nt) {
            bfrag8 b = *((const bfrag8*)(Wlds + ((size_t)((nt * 4 + kc) * 64 + l)) * 8));
            acc[nt] = __builtin_amdgcn_mfma_f32_16x16x32_bf16(a, b, acc[nt], 0, 0, 0);
        }
    }

    // store: C/D layout col = nt*16 + m, row = w*16 + quad*4 + r
    #pragma unroll
    for (int nt = 0; nt < 8; ++nt) {
        #pragma unroll
        for (int r = 0; r < 4; ++r) {
            int row = row0 + w * 16 + quad * 4 + r;
            if (row < NN) out16[(size_t)row * 128 + nt * 16 + m] = (unsigned short)f2bf(acc[nt][r]);
        }
    }
}

// ---------------- CSR aggregation: one wave per node, bf16 gather, fp32 accumulate ----------------
__global__ __launch_bounds__(256) void csr_agg_k(const int* __restrict__ row_ptr,
                                                 const int* __restrict__ csr_src,
                                                 const unsigned int* __restrict__ hw16,
                                                 const float* __restrict__ bias,
                                                 const float* __restrict__ dinv,
                                                 float* __restrict__ out) {
    int node = (blockIdx.x * 256 + threadIdx.x) >> 6;
    if (node >= NN) return;
    int lane = threadIdx.x & 63;

    float di = dinv[node];
    float sw = di * di;
    float2 b = ((const float2*)bias)[lane];
    unsigned int hs = hw16[(size_t)node * 64 + lane];
    float selfx = b.x + bf_lo(hs) * sw;
    float selfy = b.y + bf_hi(hs) * sw;

    float accx = 0.f, accy = 0.f, acc2x = 0.f, acc2y = 0.f;

    int j = row_ptr[node];
    int j1 = row_ptr[node + 1];
    for (; j + 3 < j1; j += 4) {
        int s0 = csr_src[j + 0], s1 = csr_src[j + 1];
        int s2 = csr_src[j + 2], s3 = csr_src[j + 3];
        float w0 = dinv[s0], w1 = dinv[s1], w2 = dinv[s2], w3 = dinv[s3];
        unsigned int v0 = hw16[(size_t)s0 * 64 + lane];
        unsigned int v1 = hw16[(size_t)s1 * 64 + lane];
        unsigned int v2 = hw16[(size_t)s2 * 64 + lane];
        unsigned int v3 = hw16[(size_t)s3 * 64 + lane];
        accx  += bf_lo(v0) * w0 + bf_lo(v1) * w1;
        accy  += bf_hi(v0) * w0 + bf_hi(v1) * w1;
        acc2x += bf_lo(v2) * w2 + bf_lo(v3) * w3;
        acc2y += bf_hi(v2) * w2 + bf_hi(v3) * w3;
    }
    for (; j < j1; ++j) {
        int s = csr_src[j];
        float w = dinv[s];
        unsigned int v = hw16[(size_t)s * 64 + lane];
        accx += bf_lo(v) * w;
        accy += bf_hi(v) * w;
    }
    float ox = selfx + di * (accx + acc2x);
    float oy = selfy + di * (accy + acc2y);
    ((float2*)out)[(size_t)node * 64 + lane] = make_float2(ox, oy);
}

// ---------------- batchnorm stats ----------------
__global__ __launch_bounds__(256) void bn_stats_k(const float* __restrict__ h, float* __restrict__ sums) {
    int c = threadIdx.x & 127;
    int half = threadIdx.x >> 7;
    int r0 = blockIdx.x * 128 + half;
    float s = 0.f, ss = 0.f;
    #pragma unroll 4
    for (int i = 0; i < 64; ++i) {
        int r = r0 + i * 2;
        if (r < NN) {
            float v = h[(size_t)r * 128 + c];
            s += v; ss += v * v;
        }
    }
    __shared__ float sh_s[128], sh_ss[128];
    if (half == 1) { sh_s[c] = s; sh_ss[c] = ss; }
    __syncthreads();
    if (half == 0) {
        atomicAdd(&sums[c], s + sh_s[c]);
        atomicAdd(&sums[128 + c], ss + sh_ss[c]);
    }
}

__global__ __launch_bounds__(128) void bn_finalize_k(const float* __restrict__ sums,
                                                     const float* __restrict__ g,
                                                     const float* __restrict__ beta,
                                                     float* __restrict__ ss) {
    int c = threadIdx.x;
    float mean = sums[c] * (1.0f / NN);
    float var = sums[128 + c] * (1.0f / NN) - mean * mean;
    float sc = g[c] * rsqrtf(var + BN_EPS);
    ss[c] = sc;
    ss[128 + c] = beta[c] - mean * sc;
}

// ---------------- global mean pool: chunked sum + finalize ----------------
__global__ __launch_bounds__(128) void pool_sum_k(const float* __restrict__ h,
                                                  const int* __restrict__ batch,
                                                  float* __restrict__ sums) {
    int r0 = blockIdx.x * POOL_CHUNK;
    int r1 = min(r0 + POOL_CHUNK, NN);
    if (r0 >= NN) return;
    int c = threadIdx.x;
    float acc = 0.f;
    int g = batch[r0];
    for (int r = r0; r < r1; ++r) {
        int gr = batch[r];
        if (gr != g) {
            atomicAdd(&sums[g * 128 + c], acc);
            acc = 0.f;
            g = gr;
        }
        acc += h[(size_t)r * 128 + c];
    }
    atomicAdd(&sums[g * 128 + c], acc);
}

__device__ __forceinline__ int lower_bound_dev(const int* __restrict__ a, int n, int key) {
    int lo = 0, hi = n;
    while (lo < hi) {
        int mid = (lo + hi) >> 1;
        if (a[mid] < key) lo = mid + 1; else hi = mid;
    }
    return lo;
}

__global__ __launch_bounds__(128) void pool_div_k(const float* __restrict__ sums,
                                                  const int* __restrict__ batch,
                                                  float* __restrict__ pooled) {
    int g = blockIdx.x;
    int a = lower_bound_dev(batch, NN, g);
    int b = lower_bound_dev(batch, NN, g + 1);
    float inv = 1.0f / fmaxf((float)(b - a), 1.0f);
    int c = threadIdx.x;
    pooled[g * 128 + c] = sums[g * 128 + c] * inv;
}

// ---------------- MLP head ----------------
__global__ __launch_bounds__(128) void head_k(const float* __restrict__ pooled,
                                              const float* __restrict__ W0, const float* __restrict__ b0,
                                              const float* __restrict__ W1, const float* __restrict__ b1,
                                              const float* __restrict__ W2, const float* __restrict__ b2,
                                              float* __restrict__ out) {
    __shared__ float r0[128], r1[128];
    int g = blockIdx.x, t = threadIdx.x;
    r0[t] = pooled[g * 128 + t];
    __syncthreads();
    float acc = b0[t];
    for (int k = 0; k < 128; ++k) acc += r0[k] * W0[k * 128 + t];
    r1[t] = gelu_f(acc);
    __syncthreads();
    acc = b1[t];
    for (int k = 0; k < 128; ++k) acc += r1[k] * W1[k * 128 + t];
    float y = gelu_f(acc);
    __syncthreads();
    r0[t] = y;
    __syncthreads();
    if (t < 10) {
        acc = b2[t];
        for (int k = 0; k < 128; ++k) acc += r0[k] * W2[k * 10 + t];
        out[g * 10 + t] = acc;
    }
}

extern "C" void kernel_launch(void* const* d_in, const int* in_sizes, int n_in,
                              void* d_out, int out_size, void* d_ws, size_t ws_size,
                              hipStream_t stream) {
    const float* x      = (const float*)d_in[0];
    const int*   ei     = (const int*)d_in[1];
    const int*   batch  = (const int*)d_in[2];
    const float* Wb0    = (const float*)d_in[4];
    const float* bb0    = (const float*)d_in[5];
    const float* gb0    = (const float*)d_in[6];
    const float* betab0 = (const float*)d_in[7];
    const float* Wb1    = (const float*)d_in[8];
    const float* bb1    = (const float*)d_in[9];
    const float* Wa0    = (const float*)d_in[10];
    const float* ba0    = (const float*)d_in[11];
    const float* ga0    = (const float*)d_in[12];
    const float* bea0   = (const float*)d_in[13];
    const float* Wa1    = (const float*)d_in[14];
    const float* ba1    = (const float*)d_in[15];
    const float* ga1    = (const float*)d_in[16];
    const float* bea1   = (const float*)d_in[17];
    const float* Wa2    = (const float*)d_in[18];
    const float* ba2    = (const float*)d_in[19];
    const float* Wh0    = (const float*)d_in[20];
    const float* bh0    = (const float*)d_in[21];
    const float* Wh1    = (const float*)d_in[22];
    const float* bh1    = (const float*)d_in[23];
    const float* Wh2    = (const float*)d_in[24];
    const float* bh2    = (const float*)d_in[25];
    float* out = (float*)d_out;

    char* ws = (char*)d_ws;
    unsigned int* hw16 = (unsigned int*)ws;            ws += (size_t)NN * 64 * 4;   // bf16 GEMM out
    float* bufB    = (float*)ws;                       ws += (size_t)NN * CH * 4;
    float* bufC    = (float*)ws;                       ws += (size_t)NN * CH * 4;
    int*   cnt     = (int*)ws;                         ws += (size_t)NN * 4;
    float* dinv    = (float*)ws;                       ws += (size_t)NN * 4;
    int*   row_ptr = (int*)ws;                         ws += (size_t)(NN + 1) * 4;
    int*   fill    = (int*)ws;                         ws += (size_t)NN * 4;
    int*   csr_src = (int*)ws;                         ws += (size_t)NE * 4;
    unsigned short* wf = (unsigned short*)ws;          ws += (size_t)5 * 16384 * 2; // 5 packed W
    int*   bsum    = (int*)ws;                         ws += 256 * 4;
    int*   boff    = (int*)ws;                         ws += 256 * 4;
    float* bnss    = (float*)ws;                       ws += 256 * 4;
    float* ssbuf   = (float*)ws;                       ws += 256 * 4;
    float* psum    = (float*)ws;                       ws += (size_t)NG * CH * 4;
    float* pooled  = (float*)ws;                       ws += (size_t)NG * CH * 4;

    unsigned short* wfb0 = wf;
    unsigned short* wfb1 = wf + 16384;
    unsigned short* wfa0 = wf + 2 * 16384;
    unsigned short* wfa1 = wf + 3 * 16384;
    unsigned short* wfa2 = wf + 4 * 16384;

    // W packing (independent of CSR build)
    wconv_k<<<8, 256, 0, stream>>>(Wb0, wfb0);
    wconv_k<<<8, 256, 0, stream>>>(Wb1, wfb1);
    wconv_k<<<8, 256, 0, stream>>>(Wa0, wfa0);
    wconv_k<<<8, 256, 0, stream>>>(Wa1, wfa1);
    wconv_k<<<8, 256, 0, stream>>>(Wa2, wfa2);

    // CSR build
    hipMemsetAsync(cnt, 0, NN * sizeof(int), stream);
    hist_k<<<(NE + 255) / 256, 256, 0, stream>>>(ei, cnt);
    dinv_k<<<(NN + 255) / 256, 256, 0, stream>>>(cnt, dinv);
    blk_sum_k<<<NBLK, 256, 0, stream>>>(cnt, bsum);
    blk_scan_k<<<1, 256, 0, stream>>>(bsum, boff, row_ptr);
    emit_k<<<NBLK, 256, 0, stream>>>(cnt, boff, row_ptr, fill);
    scatter_k<<<(NE + 255) / 256, 256, 0, stream>>>(ei, row_ptr, fill, csr_src);

    auto conv = [&](const float* in, const unsigned short* wfrag, const float* b,
                    const float* ss, float* o) {
        gemm_k<<<(NN + 63) / 64, 256, 0, stream>>>(in, wfrag, ss, (unsigned short*)hw16);
        csr_agg_k<<<(NN * 64 + 255) / 256, 256, 0, stream>>>(row_ptr, csr_src, hw16, b, dinv, o);
    };
    auto bn_stats = [&](const float* h, const float* g, const float* beta) {
        hipMemsetAsync(bnss, 0, 256 * sizeof(float), stream);
        bn_stats_k<<<(NN + 127) / 128, 256, 0, stream>>>(h, bnss);
        bn_finalize_k<<<1, 128, 0, stream>>>(bnss, g, beta, ssbuf);
    };

    conv(x, wfb0, bb0, nullptr, bufB);           // conv b0
    bn_stats(bufB, gb0, betab0);
    conv(bufB, wfb1, bb1, ssbuf, bufC);          // conv b1 (A-load: gelu(bn(h)))
    conv(bufC, wfa0, ba0, nullptr, bufB);        // conv a0
    bn_stats(bufB, ga0, bea0);
    conv(bufB, wfa1, ba1, ssbuf, bufC);          // conv a1
    bn_stats(bufC, ga1, bea1);
    conv(bufC, wfa2, ba2, ssbuf, bufB);          // conv a2

    hipMemsetAsync(psum, 0, NG * CH * sizeof(float), stream);
    pool_sum_k<<<(NN + POOL_CHUNK - 1) / POOL_CHUNK, 128, 0, stream>>>(bufB, batch, psum);
    pool_div_k<<<NG, 128, 0, stream>>>(psum, batch, pooled);
    head_k<<<NG, 128, 0, stream>>>(pooled, Wh0, bh0, Wh1, bh1, Wh2, bh2, out);
}